// Round 8
// baseline (1817.538 us; speedup 1.0000x reference)
//
#include <hip/hip_runtime.h>
#include <hip/hip_bf16.h>
#include <math.h>

// Problem constants
#define B_   2048
#define T_   48
#define H_   512
#define E_   256
#define V_   128
#define ENC_ 1024
#define H3_  1536   // 3*H
#define BH_  (B_ * H_)
#define NBLK_ 512   // persistent grid size (2 blocks/CU on 256 CUs)

typedef __attribute__((ext_vector_type(8))) short bf16x8;   // 8 bf16 = 4 VGPRs
typedef __attribute__((ext_vector_type(4))) float f32x4;
typedef unsigned short ushort_t;

#if defined(__has_builtin)
#if __has_builtin(__builtin_amdgcn_global_load_lds)
#define HAVE_ASYNC 1
#endif
#endif
#ifndef HAVE_ASYNC
#define HAVE_ASYNC 0
#endif

__device__ __forceinline__ void stage16(const ushort_t* g, ushort_t* l, int lane)
{
#if HAVE_ASYNC
    __builtin_amdgcn_global_load_lds(
        (const __attribute__((address_space(1))) unsigned int*)g,
        (__attribute__((address_space(3))) unsigned int*)l, 16, 0, 0);
#else
    *(bf16x8*)(l + lane * 8) = *(const bf16x8*)g;
#endif
}

__device__ __forceinline__ float sigmoidf_(float x) { return 1.0f / (1.0f + expf(-x)); }

// Block tile mapping: i0 slices pinned per XCD; m0 spans XCDs.
__device__ __forceinline__ void tile_map(int lin, int& m0, int& i0)
{
    i0 = ((((lin & 7) << 1) | ((lin >> 3) & 1))) * 32;
    m0 = (lin >> 4) * 64;
}

// ---------------------------------------------------------------------------
// fp32 tiled GEMM (xe1 setup only)
// ---------------------------------------------------------------------------
constexpr int BM = 64, BN = 64, BK = 16;

__global__ __launch_bounds__(256) void gemm_f32(
    const float* __restrict__ A, const float* __restrict__ Bm,
    const float* __restrict__ bias, float* __restrict__ C,
    int M, int N, int K)
{
    __shared__ float As[BK][BM + 4];
    __shared__ float Bs[BK][BN + 4];

    const int tid = threadIdx.x;
    const int bm = blockIdx.y * BM;
    const int bn = blockIdx.x * BN;
    const int tm = (tid >> 4) * 4;
    const int tn = (tid & 15) * 4;
    const int lmA = tid >> 2;
    const int lkA = (tid & 3) * 4;
    const int lkB = tid >> 4;
    const int lnB = (tid & 15) * 4;

    float acc[4][4] = {};

    for (int k0 = 0; k0 < K; k0 += BK) {
        float4 av  = *(const float4*)(A  + (size_t)(bm + lmA) * K + (k0 + lkA));
        float4 bv4 = *(const float4*)(Bm + (size_t)(k0 + lkB) * N + (bn + lnB));
        As[lkA + 0][lmA] = av.x;
        As[lkA + 1][lmA] = av.y;
        As[lkA + 2][lmA] = av.z;
        As[lkA + 3][lmA] = av.w;
        *(float4*)&Bs[lkB][lnB] = bv4;
        __syncthreads();

        #pragma unroll
        for (int k = 0; k < BK; ++k) {
            float4 a = *(const float4*)&As[k][tm];
            float4 b = *(const float4*)&Bs[k][tn];
            acc[0][0] += a.x * b.x; acc[0][1] += a.x * b.y; acc[0][2] += a.x * b.z; acc[0][3] += a.x * b.w;
            acc[1][0] += a.y * b.x; acc[1][1] += a.y * b.y; acc[1][2] += a.y * b.z; acc[1][3] += a.y * b.w;
            acc[2][0] += a.z * b.x; acc[2][1] += a.z * b.y; acc[2][2] += a.z * b.z; acc[2][3] += a.z * b.w;
            acc[3][0] += a.w * b.x; acc[3][1] += a.w * b.y; acc[3][2] += a.w * b.z; acc[3][3] += a.w * b.w;
        }
        __syncthreads();
    }

    #pragma unroll
    for (int r = 0; r < 4; ++r)
        #pragma unroll
        for (int c = 0; c < 4; ++c) {
            float v = acc[r][c];
            if (bias) v += bias[bn + tn + c];
            C[(size_t)(bm + tm + r) * N + (bn + tn + c)] = v;
        }
}

// ---------------------------------------------------------------------------
// Weight transpose + bf16 convert (one-time)
// ---------------------------------------------------------------------------
__global__ __launch_bounds__(256) void transpose_to_bf16(
    const float* __restrict__ W, __hip_bfloat16* __restrict__ Wt, int K, int N)
{
    __shared__ float tile[32][33];
    const int bk = blockIdx.y * 32, bn = blockIdx.x * 32;
    const int tx = threadIdx.x & 31, ty = threadIdx.x >> 5;
    #pragma unroll
    for (int i = ty; i < 32; i += 8)
        tile[i][tx] = W[(size_t)(bk + i) * N + (bn + tx)];
    __syncthreads();
    #pragma unroll
    for (int i = ty; i < 32; i += 8)
        Wt[(size_t)(bn + i) * K + (bk + tx)] = __float2bfloat16(tile[tx][i]);
}

__global__ __launch_bounds__(256) void transpose_split(
    const float* __restrict__ W, __hip_bfloat16* __restrict__ Whi,
    __hip_bfloat16* __restrict__ Wlo, int K, int N)
{
    __shared__ float tile[32][33];
    const int bk = blockIdx.y * 32, bn = blockIdx.x * 32;
    const int tx = threadIdx.x & 31, ty = threadIdx.x >> 5;
    #pragma unroll
    for (int i = ty; i < 32; i += 8)
        tile[i][tx] = W[(size_t)(bk + i) * N + (bn + tx)];
    __syncthreads();
    #pragma unroll
    for (int i = ty; i < 32; i += 8) {
        const float v = tile[tx][i];
        const __hip_bfloat16 h = __float2bfloat16(v);
        Whi[(size_t)(bn + i) * K + (bk + tx)] = h;
        Wlo[(size_t)(bn + i) * K + (bk + tx)] = __float2bfloat16(v - __bfloat162float(h));
    }
}

__global__ __launch_bounds__(256) void split_cast(
    const float* __restrict__ x, __hip_bfloat16* __restrict__ hi,
    __hip_bfloat16* __restrict__ lo, int n)
{
    const int i0 = (blockIdx.x * 256 + threadIdx.x) * 4;
    if (i0 >= n) return;
    const float4 v = *(const float4*)(x + i0);
    const float vv[4] = { v.x, v.y, v.z, v.w };
    #pragma unroll
    for (int j = 0; j < 4; ++j) {
        const __hip_bfloat16 h = __float2bfloat16(vv[j]);
        hi[i0 + j] = h;
        lo[i0 + j] = __float2bfloat16(vv[j] - __bfloat162float(h));
    }
}

// ---------------------------------------------------------------------------
// Exact-ish MFMA h0 init: C = ehi@Whi^T + elo@Whi^T + ehi@Wlo^T  (K=1024).
// ---------------------------------------------------------------------------
__global__ __launch_bounds__(256, 2) void init_mfma(
    const ushort_t* __restrict__ ehi, const ushort_t* __restrict__ elo,
    const ushort_t* __restrict__ w1hi, const ushort_t* __restrict__ w1lo,
    const ushort_t* __restrict__ w2hi, const ushort_t* __restrict__ w2lo,
    float* __restrict__ h1f, __hip_bfloat16* __restrict__ h1b,
    float* __restrict__ h2f, __hip_bfloat16* __restrict__ h2b)
{
    const ushort_t* whi = blockIdx.z ? w2hi : w1hi;
    const ushort_t* wlo = blockIdx.z ? w2lo : w1lo;
    float* hf = blockIdx.z ? h2f : h1f;
    __hip_bfloat16* hb = blockIdx.z ? h2b : h1b;

    __shared__ __attribute__((aligned(16))) ushort_t Ahi[2][4096];
    __shared__ __attribute__((aligned(16))) ushort_t Alo[2][4096];
    __shared__ __attribute__((aligned(16))) ushort_t Bhi[2][2048];
    __shared__ __attribute__((aligned(16))) ushort_t Blo[2][2048];

    const int tid  = threadIdx.x;
    const int lane = tid & 63;
    const int w    = tid >> 6;
    const int ln   = lane & 15;
    const int kg   = lane >> 4;
    const int wr   = w >> 1, wc = w & 1;
    const int m0   = blockIdx.y * 64;
    const int i0   = blockIdx.x * 32;

    const int crow = lane >> 3;
    const int ckof = ((lane & 7) ^ crow) * 8;
    const int ko0 = (kg * 8) ^ ((ln & 7) * 8);
    const int ko1 = (32 + kg * 8) ^ ((ln & 7) * 8);

    auto STG = [&](int pb, int k0) {
        #pragma unroll
        for (int c = w; c < 24; c += 4) {
            const ushort_t* g; ushort_t* l;
            if (c < 8) {
                g = ehi + (size_t)(m0 + c * 8 + crow) * ENC_ + k0 + ckof;
                l = &Ahi[pb][c * 512];
            } else if (c < 16) {
                const int cc = c - 8;
                g = elo + (size_t)(m0 + cc * 8 + crow) * ENC_ + k0 + ckof;
                l = &Alo[pb][cc * 512];
            } else if (c < 20) {
                const int cc = c - 16;
                g = whi + (size_t)(i0 + cc * 8 + crow) * ENC_ + k0 + ckof;
                l = &Bhi[pb][cc * 512];
            } else {
                const int cc = c - 20;
                g = wlo + (size_t)(i0 + cc * 8 + crow) * ENC_ + k0 + ckof;
                l = &Blo[pb][cc * 512];
            }
            stage16(g, l, lane);
        }
    };

    f32x4 acc[2] = {};
    STG(0, 0);
    __syncthreads();
    int buf = 0;
    for (int k0 = 0; k0 < ENC_; k0 += 64) {
        if (k0 + 64 < ENC_) STG(buf ^ 1, k0 + 64);
        #pragma unroll
        for (int kk = 0; kk < 2; ++kk) {
            const int ko = kk ? ko1 : ko0;
            bf16x8 ah[2], al[2], bh, bl;
            #pragma unroll
            for (int fm = 0; fm < 2; ++fm) {
                ah[fm] = *(const bf16x8*)(&Ahi[buf][(wr * 32 + fm * 16 + ln) * 64 + ko]);
                al[fm] = *(const bf16x8*)(&Alo[buf][(wr * 32 + fm * 16 + ln) * 64 + ko]);
            }
            bh = *(const bf16x8*)(&Bhi[buf][(wc * 16 + ln) * 64 + ko]);
            bl = *(const bf16x8*)(&Blo[buf][(wc * 16 + ln) * 64 + ko]);
            #pragma unroll
            for (int fm = 0; fm < 2; ++fm) {
                acc[fm] = __builtin_amdgcn_mfma_f32_16x16x32_bf16(ah[fm], bh, acc[fm], 0, 0, 0);
                acc[fm] = __builtin_amdgcn_mfma_f32_16x16x32_bf16(al[fm], bh, acc[fm], 0, 0, 0);
                acc[fm] = __builtin_amdgcn_mfma_f32_16x16x32_bf16(ah[fm], bl, acc[fm], 0, 0, 0);
            }
        }
        __syncthreads();
        buf ^= 1;
    }

    const int i = i0 + wc * 16 + ln;
    #pragma unroll
    for (int fm = 0; fm < 2; ++fm)
        #pragma unroll
        for (int r = 0; r < 4; ++r) {
            const int b = m0 + wr * 32 + fm * 16 + kg * 4 + r;
            const float v = acc[fm][r];
            hf[(size_t)b * H_ + i] = v;
            hb[(size_t)b * H_ + i] = __float2bfloat16(v);
        }
}

// ---------------------------------------------------------------------------
// Gate-operand prefetch: tgt ids (+ optional xe1 gather) for step t.
// Read-only inputs -> stale-safe -> may be issued BEFORE a grid barrier.
// ---------------------------------------------------------------------------
__device__ __forceinline__ void gate_prefetch(
    const int* __restrict__ tgt, const float* __restrict__ xe1,
    int m0, int wr, int kg, int i, int t, bool want_x,
    int (&ids)[4], float (&xz)[4], float (&xr)[4], float (&xh)[4])
{
    #pragma unroll
    for (int r = 0; r < 4; ++r) {
        const int b = m0 + wr * 16 + kg * 4 + r;
        ids[r] = tgt[(size_t)b * T_ + t];
    }
    if (want_x) {
        #pragma unroll
        for (int r = 0; r < 4; ++r) {
            const float* xg = xe1 + (size_t)ids[r] * H3_;
            xz[r] = xg[i]; xr[r] = xg[H_ + i]; xh[r] = xg[2 * H_ + i];
        }
    }
}

// ---------------------------------------------------------------------------
// Fused phase, 512 threads (8 waves: 4 wr x 2 wc), 64 rows x 32 i tiles.
// MODE 0 = l2(t2)+l1(t1) one K-loop (h1 staged once, 3 GEMM consumers);
// MODE 1 = l1 only; MODE 2 = l2 only.
// LDS: A1[2][4096] | A2[2][4096] | B1 6144 | B2 6144 | B3 6144 = 68 KB.
// ---------------------------------------------------------------------------
template<int MODE>
__device__ __forceinline__ void fused_phase(
    ushort_t* lds, int m0, int i0, int i,
    const int (&ids1)[4], const float (&xgz)[4], const float (&xgr)[4], const float (&xgh)[4],
    const int (&ids2)[4],
    const ushort_t* __restrict__ rk1t,
    float rbz, float rbr, float rbh,
    const ushort_t* __restrict__ k2t, const ushort_t* __restrict__ rk2t,
    float bxz, float bxr, float bxh, float brz, float brr, float brh,
    const ushort_t* __restrict__ h1cur,
    const ushort_t* __restrict__ h2cur, size_t h2s,
    __hip_bfloat16* __restrict__ h1nxt,
    __hip_bfloat16* __restrict__ sout, size_t souts,
    float (&hv1)[4], float (&hv2)[4])
{
    ushort_t* A1l = lds;                // 2 x 4096
    ushort_t* A2l = lds + 8192;         // 2 x 4096
    ushort_t* B1l = lds + 16384;        // rk1 strips
    ushort_t* B2l = lds + 22528;        // k2 strips
    ushort_t* B3l = lds + 28672;        // rk2 strips

    const int tid = threadIdx.x, lane = tid & 63, w = tid >> 6;
    const int ln = lane & 15, kg = lane >> 4, wr = w >> 1;
    const int crow = lane >> 3;
    const int ckof = ((lane & 7) ^ crow) * 8;
    const int ko0 = (kg * 8) ^ ((ln & 7) * 8);
    const int ko1 = (32 + kg * 8) ^ ((ln & 7) * 8);

    constexpr int NA = (MODE == 1) ? 8 : 16;
    constexpr int NB = (MODE == 0) ? 36 : ((MODE == 1) ? 12 : 24);

    auto STAGE_A = [&](int pb, int k0) {
        #pragma unroll
        for (int c = w; c < NA; c += 8) {
            const ushort_t* g; ushort_t* l;
            if (c < 8) {
                g = h1cur + (size_t)(m0 + c * 8 + crow) * H_ + k0 + ckof;
                l = A1l + pb * 4096 + c * 512;
            } else {
                const int cc = c - 8;
                g = h2cur + (size_t)(m0 + cc * 8 + crow) * h2s + k0 + ckof;
                l = A2l + pb * 4096 + cc * 512;
            }
            stage16(g, l, lane);
        }
    };
    auto STAGE_B = [&](int k0) {
        #pragma unroll
        for (int c = w; c < NB; c += 8) {
            const ushort_t* g; ushort_t* l;
            if (MODE == 1) {
                g = rk1t + (size_t)((c >> 2) * H_ + i0 + (c & 3) * 8 + crow) * H_ + k0 + ckof;
                l = B1l + c * 512;
            } else if (MODE == 2) {
                if (c < 12) {
                    g = k2t + (size_t)((c >> 2) * H_ + i0 + (c & 3) * 8 + crow) * H_ + k0 + ckof;
                    l = B2l + c * 512;
                } else {
                    const int d = c - 12;
                    g = rk2t + (size_t)((d >> 2) * H_ + i0 + (d & 3) * 8 + crow) * H_ + k0 + ckof;
                    l = B3l + d * 512;
                }
            } else {
                if (c < 12) {
                    g = rk1t + (size_t)((c >> 2) * H_ + i0 + (c & 3) * 8 + crow) * H_ + k0 + ckof;
                    l = B1l + c * 512;
                } else if (c < 24) {
                    const int d = c - 12;
                    g = k2t + (size_t)((d >> 2) * H_ + i0 + (d & 3) * 8 + crow) * H_ + k0 + ckof;
                    l = B2l + d * 512;
                } else {
                    const int d = c - 24;
                    g = rk2t + (size_t)((d >> 2) * H_ + i0 + (d & 3) * 8 + crow) * H_ + k0 + ckof;
                    l = B3l + d * 512;
                }
            }
            stage16(g, l, lane);
        }
    };

    f32x4 acc1[3] = {};   // l1
    f32x4 accx[3] = {};   // l2 x-proj
    f32x4 accr[3] = {};   // l2 recurrent

    STAGE_A(0, 0);
    STAGE_B(0);
    __syncthreads();
    int buf = 0;
    for (int k0 = 0; k0 < H_; k0 += 64) {
        const bool more = (k0 + 64 < H_);
        if (more) STAGE_A(buf ^ 1, k0 + 64);   // async A prefetch, stays in flight

        bf16x8 a1f[2], a2f[2], b1f[2][3], b2f[2][3], b3f[2][3];
        #pragma unroll
        for (int kk = 0; kk < 2; ++kk) {
            const int ko = kk ? ko1 : ko0;
            a1f[kk] = *(const bf16x8*)(A1l + buf * 4096 + (wr * 16 + ln) * 64 + ko);
            if (MODE != 1)
                a2f[kk] = *(const bf16x8*)(A2l + buf * 4096 + (wr * 16 + ln) * 64 + ko);
            #pragma unroll
            for (int g = 0; g < 3; ++g) {
                if (MODE != 2)
                    b1f[kk][g] = *(const bf16x8*)(B1l + g * 2048 + ((w & 1) * 16 + ln) * 64 + ko);
                if (MODE != 1) {
                    b2f[kk][g] = *(const bf16x8*)(B2l + g * 2048 + ((w & 1) * 16 + ln) * 64 + ko);
                    b3f[kk][g] = *(const bf16x8*)(B3l + g * 2048 + ((w & 1) * 16 + ln) * 64 + ko);
                }
            }
        }
        // my ds_reads retired -> wave-sync WITHOUT vmcnt drain -> restage B
        __builtin_amdgcn_sched_barrier(0);
        asm volatile("s_waitcnt lgkmcnt(0)" ::: "memory");
        __builtin_amdgcn_sched_barrier(0);
        __builtin_amdgcn_s_barrier();
        if (more) STAGE_B(k0 + 64);

        #pragma unroll
        for (int kk = 0; kk < 2; ++kk)
            #pragma unroll
            for (int g = 0; g < 3; ++g) {
                if (MODE != 2)
                    acc1[g] = __builtin_amdgcn_mfma_f32_16x16x32_bf16(
                        a1f[kk], b1f[kk][g], acc1[g], 0, 0, 0);
                if (MODE != 1) {
                    accx[g] = __builtin_amdgcn_mfma_f32_16x16x32_bf16(
                        a1f[kk], b2f[kk][g], accx[g], 0, 0, 0);
                    accr[g] = __builtin_amdgcn_mfma_f32_16x16x32_bf16(
                        a2f[kk], b3f[kk][g], accr[g], 0, 0, 0);
                }
            }
        __syncthreads();   // drains vmcnt: A(next)+B(next) landed
        buf ^= 1;
    }

    if (MODE != 2) {
        #pragma unroll
        for (int r = 0; r < 4; ++r) {
            const int b = m0 + wr * 16 + kg * 4 + r;
            const float hvv = hv1[r];
            float z  = sigmoidf_(xgz[r] + acc1[0][r] + rbz);
            float rr = sigmoidf_(xgr[r] + acc1[1][r] + rbr);
            float hh = tanhf(xgh[r] + rr * (acc1[2][r] + rbh));
            float hn = (ids1[r] != 0) ? (z * hvv + (1.0f - z) * hh) : hvv;
            hv1[r] = hn;
            h1nxt[(size_t)b * H_ + i] = __float2bfloat16(hn);
        }
    }
    if (MODE != 1) {
        #pragma unroll
        for (int r = 0; r < 4; ++r) {
            const int b = m0 + wr * 16 + kg * 4 + r;
            const float hvv = hv2[r];
            float z  = sigmoidf_((accx[0][r] + bxz) + (accr[0][r] + brz));
            float rr = sigmoidf_((accx[1][r] + bxr) + (accr[1][r] + brr));
            float hh = tanhf((accx[2][r] + bxh) + rr * (accr[2][r] + brh));
            float hn = (ids2[r] != 0) ? (z * hvv + (1.0f - z) * hh) : hvv;
            hv2[r] = hn;
            sout[(size_t)b * souts + i] = __float2bfloat16(hn);
        }
    }
}

// ---------------------------------------------------------------------------
// Standalone per-step wrappers (fallback path): global fp32 carry. 512 thr.
// ---------------------------------------------------------------------------
__global__ __launch_bounds__(512, 4) void l1_fused(
    const int* __restrict__ tgt, int t,
    const float* __restrict__ xe1, const ushort_t* __restrict__ rkt,
    const float* __restrict__ rb,
    const float* __restrict__ hf_cur, const ushort_t* __restrict__ hb_cur,
    float* __restrict__ hf_nxt, __hip_bfloat16* __restrict__ hb_nxt)
{
    __shared__ __attribute__((aligned(16))) ushort_t lds[34816];
    int m0, i0; tile_map(blockIdx.x, m0, i0);
    const int tid = threadIdx.x, lane = tid & 63, w = tid >> 6;
    const int ln = lane & 15, kg = lane >> 4, wr = w >> 1, wc = w & 1;
    const int i = i0 + wc * 16 + ln;

    float hv1[4], hv2[4];
    int ids1[4], ids2[4];
    float xz[4], xr[4], xh[4];
    gate_prefetch(tgt, xe1, m0, wr, kg, i, t, true, ids1, xz, xr, xh);
    #pragma unroll
    for (int r = 0; r < 4; ++r)
        hv1[r] = hf_cur[(size_t)(m0 + wr * 16 + kg * 4 + r) * H_ + i];
    #pragma unroll
    for (int r = 0; r < 4; ++r) { ids2[r] = 0; hv2[r] = 0.f; }

    fused_phase<1>(lds, m0, i0, i, ids1, xz, xr, xh, ids2, rkt,
                   rb[i], rb[H_ + i], rb[2 * H_ + i],
                   nullptr, nullptr, 0.f, 0.f, 0.f, 0.f, 0.f, 0.f,
                   hb_cur, nullptr, 0, hb_nxt, nullptr, 0, hv1, hv2);

    #pragma unroll
    for (int r = 0; r < 4; ++r)
        hf_nxt[(size_t)(m0 + wr * 16 + kg * 4 + r) * H_ + i] = hv1[r];
}

__global__ __launch_bounds__(512, 4) void l2_fused(
    const int* __restrict__ tgt, int t,
    const ushort_t* __restrict__ k2t, const ushort_t* __restrict__ rk2t,
    const float* __restrict__ bx, const float* __restrict__ br,
    const ushort_t* __restrict__ s1b,
    const float* __restrict__ hf_cur,
    const ushort_t* __restrict__ hb_cur, size_t hbs,
    float* __restrict__ hf_nxt,
    __hip_bfloat16* __restrict__ hbo, size_t hos)
{
    __shared__ __attribute__((aligned(16))) ushort_t lds[34816];
    int m0, i0; tile_map(blockIdx.x, m0, i0);
    const int tid = threadIdx.x, lane = tid & 63, w = tid >> 6;
    const int ln = lane & 15, kg = lane >> 4, wr = w >> 1, wc = w & 1;
    const int i = i0 + wc * 16 + ln;

    float hv1[4], hv2[4];
    int ids1[4], ids2[4];
    float xz[4], xr[4], xh[4];
    gate_prefetch(tgt, nullptr, m0, wr, kg, i, t, false, ids2, xz, xr, xh);
    #pragma unroll
    for (int r = 0; r < 4; ++r)
        hv2[r] = hf_cur[(size_t)(m0 + wr * 16 + kg * 4 + r) * H_ + i];
    #pragma unroll
    for (int r = 0; r < 4; ++r) { ids1[r] = 0; hv1[r] = 0.f; xz[r] = xr[r] = xh[r] = 0.f; }

    fused_phase<2>(lds, m0, i0, i, ids1, xz, xr, xh, ids2, nullptr,
                   0.f, 0.f, 0.f,
                   k2t, rk2t,
                   bx[i], bx[H_ + i], bx[2 * H_ + i],
                   br[i], br[H_ + i], br[2 * H_ + i],
                   s1b, hb_cur, hbs, nullptr, hbo, hos, hv1, hv2);

    #pragma unroll
    for (int r = 0; r < 4; ++r)
        hf_nxt[(size_t)(m0 + wr * 16 + kg * 4 + r) * H_ + i] = hv2[r];
}

// ---------------------------------------------------------------------------
// Grid barrier, monotonic counter, RELAXED spin (no per-poll cache inval).
// ---------------------------------------------------------------------------
__device__ __forceinline__ void grid_barrier(unsigned* bar, unsigned phase)
{
    __syncthreads();
    if (threadIdx.x == 0) {
        __builtin_amdgcn_fence(__ATOMIC_RELEASE, "agent");
        const unsigned arrived =
            __hip_atomic_fetch_add(&bar[0], 1u, __ATOMIC_RELAXED, __HIP_MEMORY_SCOPE_AGENT) + 1u;
        if (arrived == (unsigned)NBLK_ * (phase + 1u)) {
            __hip_atomic_store(&bar[1], phase + 1u, __ATOMIC_RELAXED, __HIP_MEMORY_SCOPE_AGENT);
        } else {
            while (__hip_atomic_load(&bar[1], __ATOMIC_RELAXED, __HIP_MEMORY_SCOPE_AGENT) < phase + 1u)
                __builtin_amdgcn_s_sleep(4);
        }
        __builtin_amdgcn_fence(__ATOMIC_ACQUIRE, "agent");
    }
    __syncthreads();
}

// ---------------------------------------------------------------------------
// Persistent recurrence: fused l2(p)+l1(p+1) phases, 48 barriers total.
// Gate operands for the NEXT phase are prefetched BEFORE each barrier
// (read-only data -> stale-safe; registers survive the acquire fence).
// ---------------------------------------------------------------------------
__global__ __launch_bounds__(512, 4) void recurrence_all(
    const int* __restrict__ tgt, const float* __restrict__ xe1,
    const ushort_t* __restrict__ rk1t, const float* __restrict__ rb1,
    const ushort_t* __restrict__ k2t, const ushort_t* __restrict__ rk2t,
    const float* __restrict__ bx, const float* __restrict__ br,
    const float* __restrict__ h1f0, __hip_bfloat16* __restrict__ h1b,
    const float* __restrict__ h2f0, const __hip_bfloat16* __restrict__ h2b0,
    __hip_bfloat16* __restrict__ seq2b, unsigned* __restrict__ bar)
{
    __shared__ __attribute__((aligned(16))) ushort_t lds[34816];  // 68 KB
    int m0, i0; tile_map(blockIdx.x, m0, i0);
    const int tid = threadIdx.x, lane = tid & 63, w = tid >> 6;
    const int ln = lane & 15, kg = lane >> 4, wr = w >> 1, wc = w & 1;
    const int i = i0 + wc * 16 + ln;

    const float rbz = rb1[i], rbr = rb1[H_ + i], rbh = rb1[2 * H_ + i];
    const float bxz = bx[i],  bxr = bx[H_ + i],  bxh = bx[2 * H_ + i];
    const float brz = br[i],  brr = br[H_ + i],  brh = br[2 * H_ + i];

    float hv1[4], hv2[4];
    #pragma unroll
    for (int r = 0; r < 4; ++r) {
        const size_t b = (size_t)(m0 + wr * 16 + kg * 4 + r) * H_ + i;
        hv1[r] = h1f0[b];
        hv2[r] = h2f0[b];
    }

    int idsA[4], idsB[4];         // idsA: l1 step (t1); idsB: l2 step (t2)
    float xzA[4], xrA[4], xhA[4];
    gate_prefetch(tgt, xe1, m0, wr, kg, i, 0, true, idsA, xzA, xrA, xhA);

    unsigned ph = 0;

    // prologue: l1(0): h1b[0] -> h1b[1]
    fused_phase<1>(lds, m0, i0, i, idsA, xzA, xrA, xhA, idsB,
                   rk1t, rbz, rbr, rbh,
                   nullptr, nullptr, 0.f, 0.f, 0.f, 0.f, 0.f, 0.f,
                   (const ushort_t*)h1b, nullptr, 0, h1b + BH_, nullptr, 0,
                   hv1, hv2);
    // rotate: l2(0) uses ids(0); prefetch ids/xg(1) before the barrier
    #pragma unroll
    for (int r = 0; r < 4; ++r) idsB[r] = idsA[r];
    gate_prefetch(tgt, xe1, m0, wr, kg, i, 1, true, idsA, xzA, xrA, xhA);
    grid_barrier(bar, ph); ++ph;

    #pragma unroll 1
    for (int p = 0; p < T_ - 1; ++p) {
        const ushort_t* s1 = (const ushort_t*)(h1b + (size_t)((p + 1) & 1) * BH_);
        const ushort_t* a2 = (p == 0) ? (const ushort_t*)h2b0
                                      : (const ushort_t*)(seq2b + (size_t)(p - 1) * H_);
        const size_t a2s = (p == 0) ? (size_t)H_ : (size_t)T_ * H_;

        fused_phase<0>(lds, m0, i0, i, idsA, xzA, xrA, xhA, idsB,
                       rk1t, rbz, rbr, rbh,
                       k2t, rk2t, bxz, bxr, bxh, brz, brr, brh,
                       s1, a2, a2s,
                       h1b + (size_t)(p & 1) * BH_,
                       seq2b + (size_t)p * H_, (size_t)T_ * H_,
                       hv1, hv2);
        // rotate gate ops for next phase; prefetch t = p+2 before barrier
        #pragma unroll
        for (int r = 0; r < 4; ++r) idsB[r] = idsA[r];
        if (p + 2 <= T_ - 1)
            gate_prefetch(tgt, xe1, m0, wr, kg, i, p + 2, true, idsA, xzA, xrA, xhA);
        grid_barrier(bar, ph); ++ph;
    }

    // final: l2(T-1) only (idsB holds ids(T-1)); kernel end is the sync
    {
        const int p = T_ - 1;
        const ushort_t* s1 = (const ushort_t*)(h1b + (size_t)((p + 1) & 1) * BH_);
        const ushort_t* a2 = (const ushort_t*)(seq2b + (size_t)(p - 1) * H_);
        fused_phase<2>(lds, m0, i0, i, idsA, xzA, xrA, xhA, idsB,
                       nullptr, 0.f, 0.f, 0.f,
                       k2t, rk2t, bxz, bxr, bxh, brz, brr, brh,
                       s1, a2, (size_t)T_ * H_,
                       nullptr, seq2b + (size_t)p * H_, (size_t)T_ * H_,
                       hv1, hv2);
    }
}

// ---------------------------------------------------------------------------
// Softmax helpers + per-step fallback kernel (small-workspace path)
// ---------------------------------------------------------------------------
__device__ __forceinline__ void softmax_write4(
    float ax, float ay, float az, float aw, float* __restrict__ outp, int cg)
{
    float m = fmaxf(fmaxf(ax, ay), fmaxf(az, aw));
    #pragma unroll
    for (int d = 16; d >= 1; d >>= 1) m = fmaxf(m, __shfl_xor(m, d));
    float ex = __expf(ax - m), ey = __expf(ay - m),
          ez = __expf(az - m), ew = __expf(aw - m);
    float s = ex + ey + ez + ew;
    #pragma unroll
    for (int d = 16; d >= 1; d >>= 1) s += __shfl_xor(s, d);
    float inv = 1.0f / s;
    float4 o; o.x = ex * inv; o.y = ey * inv; o.z = ez * inv; o.w = ew * inv;
    *(float4*)(outp + cg * 4) = o;
}

__global__ __launch_bounds__(256) void out_softmax(
    const float* __restrict__ h2, const float* __restrict__ Wv,
    const float* __restrict__ bv, float* __restrict__ out, int t)
{
    const int tid = threadIdx.x;
    const int cg = tid & 31;
    const int rg = tid >> 5;
    const int row0 = blockIdx.x * 16;

    __shared__ float hs[16][512];
    for (int idx = tid; idx < 16 * 512; idx += 256)
        hs[idx >> 9][idx & 511] = h2[(size_t)(row0 + (idx >> 9)) * 512 + (idx & 511)];
    __syncthreads();

    const int r0 = rg * 2;
    const float4 bvv = *(const float4*)(bv + cg * 4);
    float a0x = bvv.x, a0y = bvv.y, a0z = bvv.z, a0w = bvv.w;
    float a1x = bvv.x, a1y = bvv.y, a1z = bvv.z, a1w = bvv.w;

    #pragma unroll 4
    for (int k = 0; k < 512; ++k) {
        float4 wv = *(const float4*)(Wv + (size_t)k * V_ + cg * 4);
        float h0 = hs[r0][k], h1 = hs[r0 + 1][k];
        a0x += h0 * wv.x; a0y += h0 * wv.y; a0z += h0 * wv.z; a0w += h0 * wv.w;
        a1x += h1 * wv.x; a1y += h1 * wv.y; a1z += h1 * wv.z; a1w += h1 * wv.w;
    }

    softmax_write4(a0x, a0y, a0z, a0w, out + ((size_t)(row0 + r0) * T_ + t) * V_, cg);
    softmax_write4(a1x, a1y, a1z, a1w, out + ((size_t)(row0 + r0 + 1) * T_ + t) * V_, cg);
}

// ---------------------------------------------------------------------------
// Batched MFMA vocab projection + softmax (off critical path).
// ---------------------------------------------------------------------------
__global__ __launch_bounds__(256) void proj_mfma(
    const ushort_t* __restrict__ s2, const ushort_t* __restrict__ wvt,
    const float* __restrict__ bv, float* __restrict__ out)
{
    const int lane = threadIdx.x & 63;
    const int w    = threadIdx.x >> 6;
    const int ln   = lane & 15;
    const int kg   = lane >> 4;
    const size_t row0 = (size_t)blockIdx.x * 128 + (size_t)w * 32;

    float bvl[8];
    #pragma unroll
    for (int nf = 0; nf < 8; ++nf) bvl[nf] = bv[nf * 16 + ln];

    f32x4 acc[2][8] = {};
    #pragma unroll 2
    for (int k0 = 0; k0 < H_; k0 += 32) {
        bf16x8 af[2], bf[8];
        #pragma unroll
        for (int mf = 0; mf < 2; ++mf)
            af[mf] = *(const bf16x8*)(s2 + (row0 + mf * 16 + ln) * H_ + k0 + kg * 8);
        #pragma unroll
        for (int nf = 0; nf < 8; ++nf)
            bf[nf] = *(const bf16x8*)(wvt + (size_t)(nf * 16 + ln) * H_ + k0 + kg * 8);
        #pragma unroll
        for (int mf = 0; mf < 2; ++mf)
            #pragma unroll
            for (int nf = 0; nf < 8; ++nf)
                acc[mf][nf] = __builtin_amdgcn_mfma_f32_16x16x32_bf16(
                    af[mf], bf[nf], acc[mf][nf], 0, 0, 0);
    }

    #pragma unroll
    for (int mf = 0; mf < 2; ++mf)
        #pragma unroll
        for (int q = 0; q < 4; ++q) {
            float v[8];
            float m = -1e30f;
            #pragma unroll
            for (int nf = 0; nf < 8; ++nf) { v[nf] = acc[mf][nf][q] + bvl[nf]; m = fmaxf(m, v[nf]); }
            #pragma unroll
            for (int d = 1; d <= 8; d <<= 1) m = fmaxf(m, __shfl_xor(m, d));
            float s = 0.f;
            #pragma unroll
            for (int nf = 0; nf < 8; ++nf) { v[nf] = __expf(v[nf] - m); s += v[nf]; }
            #pragma unroll
            for (int d = 1; d <= 8; d <<= 1) s += __shfl_xor(s, d);
            const float inv = 1.0f / s;
            float* op = out + (row0 + mf * 16 + kg * 4 + q) * V_;
            #pragma unroll
            for (int nf = 0; nf < 8; ++nf) op[nf * 16 + ln] = v[nf] * inv;
        }
}

// ---------------------------------------------------------------------------
// Launch
// ---------------------------------------------------------------------------
extern "C" void kernel_launch(void* const* d_in, const int* in_sizes, int n_in,
                              void* d_out, int out_size, void* d_ws, size_t ws_size,
                              hipStream_t stream)
{
    const int*   tgt  = (const int*)  d_in[0];
    const float* enc  = (const float*)d_in[1];
    const float* Wi1  = (const float*)d_in[2];
    const float* Wi2  = (const float*)d_in[3];
    const float* emb  = (const float*)d_in[4];
    const float* k1   = (const float*)d_in[5];
    const float* rk1  = (const float*)d_in[6];
    const float* b1   = (const float*)d_in[7];
    const float* k2   = (const float*)d_in[8];
    const float* rk2  = (const float*)d_in[9];
    const float* b2   = (const float*)d_in[10];
    const float* Wv   = (const float*)d_in[11];
    const float* bv   = (const float*)d_in[12];
    float* out = (float*)d_out;

    // workspace layout
    float* ws  = (float*)d_ws;
    float* xe1 = ws;                                   // [V,3H] f32
    float* h1f = xe1 + (size_t)V_ * H3_;               // [2][B*H] f32
    float* h2f = h1f + (size_t)2 * BH_;                // [2][B*H] f32
    __hip_bfloat16* h1b = (__hip_bfloat16*)(h2f + (size_t)2 * BH_);  // [2][B*H]
    __hip_bfloat16* h2b = h1b + (size_t)2 * BH_;       // [2][B*H]
    __hip_bfloat16* rk1t = h2b + (size_t)2 * BH_;      // [3H,H]
    __hip_bfloat16* k2t  = rk1t + (size_t)H3_ * H_;
    __hip_bfloat16* rk2t = k2t  + (size_t)H3_ * H_;
    __hip_bfloat16* wvt  = rk2t + (size_t)H3_ * H_;    // [V,H]
    __hip_bfloat16* ehi  = wvt + (size_t)V_ * H_;      // [B,ENC]
    __hip_bfloat16* elo  = ehi + (size_t)B_ * ENC_;
    __hip_bfloat16* w1hi = elo + (size_t)B_ * ENC_;    // [H,ENC] x4
    __hip_bfloat16* w1lo = w1hi + (size_t)H_ * ENC_;
    __hip_bfloat16* w2hi = w1lo + (size_t)H_ * ENC_;
    __hip_bfloat16* w2lo = w2hi + (size_t)H_ * ENC_;
    __hip_bfloat16* seq2b = w2lo + (size_t)H_ * ENC_;  // [B,T,H] bf16
    unsigned* bar = (unsigned*)(seq2b + (size_t)B_ * T_ * H_);  // 64 B

    const size_t need = (size_t)((char*)bar + 64 - (char*)d_ws);
    const bool batched = ws_size >= need;

    static int persist_state = -1;
    if (persist_state < 0) {
        int nb = 0;
        hipError_t e1 = hipOccupancyMaxActiveBlocksPerMultiprocessor(&nb, recurrence_all, 512, 0);
        hipDeviceProp_t prop;
        hipError_t e2 = hipGetDeviceProperties(&prop, 0);
        persist_state = (e1 == hipSuccess && e2 == hipSuccess &&
                         (long)nb * prop.multiProcessorCount >= NBLK_) ? 1 : 0;
    }
    const bool persist = batched && persist_state == 1;

    dim3 blk(256);
    dim3 blkR(512);

    // one-time: weight transposes to bf16
    transpose_to_bf16<<<dim3(H3_ / 32, H_ / 32), blk, 0, stream>>>(rk1, rk1t, H_, H3_);
    transpose_to_bf16<<<dim3(H3_ / 32, H_ / 32), blk, 0, stream>>>(k2,  k2t,  H_, H3_);
    transpose_to_bf16<<<dim3(H3_ / 32, H_ / 32), blk, 0, stream>>>(rk2, rk2t, H_, H3_);
    if (batched)
        transpose_to_bf16<<<dim3(V_ / 32, H_ / 32), blk, 0, stream>>>(Wv, wvt, H_, V_);

    // split-bf16 operands for the exact MFMA h0-init
    split_cast<<<dim3((B_ * ENC_) / 1024), blk, 0, stream>>>(enc, ehi, elo, B_ * ENC_);
    transpose_split<<<dim3(H_ / 32, ENC_ / 32), blk, 0, stream>>>(Wi1, w1hi, w1lo, ENC_, H_);
    transpose_split<<<dim3(H_ / 32, ENC_ / 32), blk, 0, stream>>>(Wi2, w2hi, w2lo, ENC_, H_);

    // xe1 = embed_table @ k1 + b1[0]  (fp32, exact)
    gemm_f32<<<dim3(H3_ / BN, V_ / BM), blk, 0, stream>>>(emb, k1, b1, xe1, V_, H3_, E_);

    // h0-init
    init_mfma<<<dim3(H_ / 32, B_ / 64, 2), blk, 0, stream>>>(
        (const ushort_t*)ehi, (const ushort_t*)elo,
        (const ushort_t*)w1hi, (const ushort_t*)w1lo,
        (const ushort_t*)w2hi, (const ushort_t*)w2lo,
        h1f, h1b, h2f, h2b);

    if (persist) {
        hipMemsetAsync(bar, 0, 64, stream);
        recurrence_all<<<dim3(NBLK_), blkR, 0, stream>>>(
            tgt, xe1, (const ushort_t*)rk1t, b1 + H3_,
            (const ushort_t*)k2t, (const ushort_t*)rk2t, b2, b2 + H3_,
            h1f, h1b, h2f, h2b, seq2b, bar);
        proj_mfma<<<dim3((B_ * T_) / 128), blk, 0, stream>>>(
            (const ushort_t*)seq2b, (const ushort_t*)wvt, bv, out);
        return;
    }

    // fallback: per-step launches
    const dim3 fgrid(NBLK_);
    for (int t = 0; t < T_; ++t) {
        const int cur = t & 1, nxt = cur ^ 1;
        float* h1f_c = h1f + (size_t)cur * BH_;
        float* h1f_n = h1f + (size_t)nxt * BH_;
        float* h2f_c = h2f + (size_t)cur * BH_;
        float* h2f_n = h2f + (size_t)nxt * BH_;
        __hip_bfloat16* h1b_c = h1b + (size_t)cur * BH_;
        __hip_bfloat16* h1b_n = h1b + (size_t)nxt * BH_;

        l1_fused<<<fgrid, blkR, 0, stream>>>(
            tgt, t, xe1, (const ushort_t*)rk1t, b1 + H3_,
            h1f_c, (const ushort_t*)h1b_c, h1f_n, h1b_n);

        const ushort_t* hb_c; size_t hbs;
        __hip_bfloat16* hbo; size_t hos;
        if (batched) {
            hb_c = (t == 0) ? (const ushort_t*)h2b
                            : (const ushort_t*)(seq2b + (size_t)(t - 1) * H_);
            hbs  = (t == 0) ? (size_t)H_ : (size_t)T_ * H_;
            hbo  = seq2b + (size_t)t * H_;
            hos  = (size_t)T_ * H_;
        } else {
            hb_c = (const ushort_t*)(h2b + (size_t)cur * BH_); hbs = H_;
            hbo  = h2b + (size_t)nxt * BH_;                    hos = H_;
        }

        l2_fused<<<fgrid, blkR, 0, stream>>>(
            tgt, t, (const ushort_t*)k2t, (const ushort_t*)rk2t, b2, b2 + H3_,
            (const ushort_t*)h1b_n, h2f_c, hb_c, hbs, h2f_n, hbo, hos);

        if (!batched)
            out_softmax<<<dim3(B_ / 16), blk, 0, stream>>>(h2f_n, Wv, bv, out, t);
    }

    if (batched)
        proj_mfma<<<dim3((B_ * T_) / 128), blk, 0, stream>>>(
            (const ushort_t*)seq2b, (const ushort_t*)wvt, bv, out);
}

// Round 9
// 1514.576 us; speedup vs baseline: 1.2000x; 1.2000x over previous
//
#include <hip/hip_runtime.h>
#include <hip/hip_bf16.h>
#include <math.h>

// Problem constants
#define B_   2048
#define T_   48
#define H_   512
#define E_   256
#define V_   128
#define ENC_ 1024
#define H3_  1536   // 3*H
#define BH_  (B_ * H_)
#define NBLK_ 512   // persistent grid size (2 blocks/CU on 256 CUs)

typedef __attribute__((ext_vector_type(8))) short bf16x8;   // 8 bf16 = 4 VGPRs
typedef __attribute__((ext_vector_type(4))) float f32x4;
typedef unsigned short ushort_t;

#if defined(__has_builtin)
#if __has_builtin(__builtin_amdgcn_global_load_lds)
#define HAVE_ASYNC 1
#endif
#endif
#ifndef HAVE_ASYNC
#define HAVE_ASYNC 0
#endif

__device__ __forceinline__ void stage16(const ushort_t* g, ushort_t* l, int lane)
{
#if HAVE_ASYNC
    __builtin_amdgcn_global_load_lds(
        (const __attribute__((address_space(1))) unsigned int*)g,
        (__attribute__((address_space(3))) unsigned int*)l, 16, 0, 0);
#else
    *(bf16x8*)(l + lane * 8) = *(const bf16x8*)g;
#endif
}

__device__ __forceinline__ float sigmoidf_(float x) { return 1.0f / (1.0f + expf(-x)); }

// r5 tile map: consecutive lin within an XCD (round-robin dispatch) covers
// 4 m-tiles x 16 i-slices => each XCD owns 256 contiguous batch rows; state
// reads stay XCD-L2-local after first touch.
__device__ __forceinline__ void tile_map(int lin, int& m0, int& i0)
{
    const int swz = (lin & 7) * 64 + (lin >> 3);
    m0 = (swz >> 4) * 64;
    i0 = (swz & 15) * 32;
}

// ---------------------------------------------------------------------------
// fp32 tiled GEMM (xe1 setup only)
// ---------------------------------------------------------------------------
constexpr int BM = 64, BN = 64, BK = 16;

__global__ __launch_bounds__(256) void gemm_f32(
    const float* __restrict__ A, const float* __restrict__ Bm,
    const float* __restrict__ bias, float* __restrict__ C,
    int M, int N, int K)
{
    __shared__ float As[BK][BM + 4];
    __shared__ float Bs[BK][BN + 4];

    const int tid = threadIdx.x;
    const int bm = blockIdx.y * BM;
    const int bn = blockIdx.x * BN;
    const int tm = (tid >> 4) * 4;
    const int tn = (tid & 15) * 4;
    const int lmA = tid >> 2;
    const int lkA = (tid & 3) * 4;
    const int lkB = tid >> 4;
    const int lnB = (tid & 15) * 4;

    float acc[4][4] = {};

    for (int k0 = 0; k0 < K; k0 += BK) {
        float4 av  = *(const float4*)(A  + (size_t)(bm + lmA) * K + (k0 + lkA));
        float4 bv4 = *(const float4*)(Bm + (size_t)(k0 + lkB) * N + (bn + lnB));
        As[lkA + 0][lmA] = av.x;
        As[lkA + 1][lmA] = av.y;
        As[lkA + 2][lmA] = av.z;
        As[lkA + 3][lmA] = av.w;
        *(float4*)&Bs[lkB][lnB] = bv4;
        __syncthreads();

        #pragma unroll
        for (int k = 0; k < BK; ++k) {
            float4 a = *(const float4*)&As[k][tm];
            float4 b = *(const float4*)&Bs[k][tn];
            acc[0][0] += a.x * b.x; acc[0][1] += a.x * b.y; acc[0][2] += a.x * b.z; acc[0][3] += a.x * b.w;
            acc[1][0] += a.y * b.x; acc[1][1] += a.y * b.y; acc[1][2] += a.y * b.z; acc[1][3] += a.y * b.w;
            acc[2][0] += a.z * b.x; acc[2][1] += a.z * b.y; acc[2][2] += a.z * b.z; acc[2][3] += a.z * b.w;
            acc[3][0] += a.w * b.x; acc[3][1] += a.w * b.y; acc[3][2] += a.w * b.z; acc[3][3] += a.w * b.w;
        }
        __syncthreads();
    }

    #pragma unroll
    for (int r = 0; r < 4; ++r)
        #pragma unroll
        for (int c = 0; c < 4; ++c) {
            float v = acc[r][c];
            if (bias) v += bias[bn + tn + c];
            C[(size_t)(bm + tm + r) * N + (bn + tn + c)] = v;
        }
}

// ---------------------------------------------------------------------------
// Weight transpose + bf16 convert (one-time)
// ---------------------------------------------------------------------------
__global__ __launch_bounds__(256) void transpose_to_bf16(
    const float* __restrict__ W, __hip_bfloat16* __restrict__ Wt, int K, int N)
{
    __shared__ float tile[32][33];
    const int bk = blockIdx.y * 32, bn = blockIdx.x * 32;
    const int tx = threadIdx.x & 31, ty = threadIdx.x >> 5;
    #pragma unroll
    for (int i = ty; i < 32; i += 8)
        tile[i][tx] = W[(size_t)(bk + i) * N + (bn + tx)];
    __syncthreads();
    #pragma unroll
    for (int i = ty; i < 32; i += 8)
        Wt[(size_t)(bn + i) * K + (bk + tx)] = __float2bfloat16(tile[tx][i]);
}

__global__ __launch_bounds__(256) void transpose_split(
    const float* __restrict__ W, __hip_bfloat16* __restrict__ Whi,
    __hip_bfloat16* __restrict__ Wlo, int K, int N)
{
    __shared__ float tile[32][33];
    const int bk = blockIdx.y * 32, bn = blockIdx.x * 32;
    const int tx = threadIdx.x & 31, ty = threadIdx.x >> 5;
    #pragma unroll
    for (int i = ty; i < 32; i += 8)
        tile[i][tx] = W[(size_t)(bk + i) * N + (bn + tx)];
    __syncthreads();
    #pragma unroll
    for (int i = ty; i < 32; i += 8) {
        const float v = tile[tx][i];
        const __hip_bfloat16 h = __float2bfloat16(v);
        Whi[(size_t)(bn + i) * K + (bk + tx)] = h;
        Wlo[(size_t)(bn + i) * K + (bk + tx)] = __float2bfloat16(v - __bfloat162float(h));
    }
}

__global__ __launch_bounds__(256) void split_cast(
    const float* __restrict__ x, __hip_bfloat16* __restrict__ hi,
    __hip_bfloat16* __restrict__ lo, int n)
{
    const int i0 = (blockIdx.x * 256 + threadIdx.x) * 4;
    if (i0 >= n) return;
    const float4 v = *(const float4*)(x + i0);
    const float vv[4] = { v.x, v.y, v.z, v.w };
    #pragma unroll
    for (int j = 0; j < 4; ++j) {
        const __hip_bfloat16 h = __float2bfloat16(vv[j]);
        hi[i0 + j] = h;
        lo[i0 + j] = __float2bfloat16(vv[j] - __bfloat162float(h));
    }
}

// ---------------------------------------------------------------------------
// Exact-ish MFMA h0 init: C = ehi@Whi^T + elo@Whi^T + ehi@Wlo^T  (K=1024).
// ---------------------------------------------------------------------------
__global__ __launch_bounds__(256, 2) void init_mfma(
    const ushort_t* __restrict__ ehi, const ushort_t* __restrict__ elo,
    const ushort_t* __restrict__ w1hi, const ushort_t* __restrict__ w1lo,
    const ushort_t* __restrict__ w2hi, const ushort_t* __restrict__ w2lo,
    float* __restrict__ h1f, __hip_bfloat16* __restrict__ h1b,
    float* __restrict__ h2f, __hip_bfloat16* __restrict__ h2b)
{
    const ushort_t* whi = blockIdx.z ? w2hi : w1hi;
    const ushort_t* wlo = blockIdx.z ? w2lo : w1lo;
    float* hf = blockIdx.z ? h2f : h1f;
    __hip_bfloat16* hb = blockIdx.z ? h2b : h1b;

    __shared__ __attribute__((aligned(16))) ushort_t Ahi[2][4096];
    __shared__ __attribute__((aligned(16))) ushort_t Alo[2][4096];
    __shared__ __attribute__((aligned(16))) ushort_t Bhi[2][2048];
    __shared__ __attribute__((aligned(16))) ushort_t Blo[2][2048];

    const int tid  = threadIdx.x;
    const int lane = tid & 63;
    const int w    = tid >> 6;
    const int ln   = lane & 15;
    const int kg   = lane >> 4;
    const int wr   = w >> 1, wc = w & 1;
    const int m0   = blockIdx.y * 64;
    const int i0   = blockIdx.x * 32;

    const int crow = lane >> 3;
    const int ckof = ((lane & 7) ^ crow) * 8;
    const int ko0 = (kg * 8) ^ ((ln & 7) * 8);
    const int ko1 = (32 + kg * 8) ^ ((ln & 7) * 8);

    auto STG = [&](int pb, int k0) {
        #pragma unroll
        for (int c = w; c < 24; c += 4) {
            const ushort_t* g; ushort_t* l;
            if (c < 8) {
                g = ehi + (size_t)(m0 + c * 8 + crow) * ENC_ + k0 + ckof;
                l = &Ahi[pb][c * 512];
            } else if (c < 16) {
                const int cc = c - 8;
                g = elo + (size_t)(m0 + cc * 8 + crow) * ENC_ + k0 + ckof;
                l = &Alo[pb][cc * 512];
            } else if (c < 20) {
                const int cc = c - 16;
                g = whi + (size_t)(i0 + cc * 8 + crow) * ENC_ + k0 + ckof;
                l = &Bhi[pb][cc * 512];
            } else {
                const int cc = c - 20;
                g = wlo + (size_t)(i0 + cc * 8 + crow) * ENC_ + k0 + ckof;
                l = &Blo[pb][cc * 512];
            }
            stage16(g, l, lane);
        }
    };

    f32x4 acc[2] = {};
    STG(0, 0);
    __syncthreads();
    int buf = 0;
    for (int k0 = 0; k0 < ENC_; k0 += 64) {
        if (k0 + 64 < ENC_) STG(buf ^ 1, k0 + 64);
        #pragma unroll
        for (int kk = 0; kk < 2; ++kk) {
            const int ko = kk ? ko1 : ko0;
            bf16x8 ah[2], al[2], bh, bl;
            #pragma unroll
            for (int fm = 0; fm < 2; ++fm) {
                ah[fm] = *(const bf16x8*)(&Ahi[buf][(wr * 32 + fm * 16 + ln) * 64 + ko]);
                al[fm] = *(const bf16x8*)(&Alo[buf][(wr * 32 + fm * 16 + ln) * 64 + ko]);
            }
            bh = *(const bf16x8*)(&Bhi[buf][(wc * 16 + ln) * 64 + ko]);
            bl = *(const bf16x8*)(&Blo[buf][(wc * 16 + ln) * 64 + ko]);
            #pragma unroll
            for (int fm = 0; fm < 2; ++fm) {
                acc[fm] = __builtin_amdgcn_mfma_f32_16x16x32_bf16(ah[fm], bh, acc[fm], 0, 0, 0);
                acc[fm] = __builtin_amdgcn_mfma_f32_16x16x32_bf16(al[fm], bh, acc[fm], 0, 0, 0);
                acc[fm] = __builtin_amdgcn_mfma_f32_16x16x32_bf16(ah[fm], bl, acc[fm], 0, 0, 0);
            }
        }
        __syncthreads();
        buf ^= 1;
    }

    const int i = i0 + wc * 16 + ln;
    #pragma unroll
    for (int fm = 0; fm < 2; ++fm)
        #pragma unroll
        for (int r = 0; r < 4; ++r) {
            const int b = m0 + wr * 32 + fm * 16 + kg * 4 + r;
            const float v = acc[fm][r];
            hf[(size_t)b * H_ + i] = v;
            hb[(size_t)b * H_ + i] = __float2bfloat16(v);
        }
}

// ---------------------------------------------------------------------------
// Layer-1 phase body. fp32 carry in registers (hv in/out); bf16 state out.
// 256 threads (4 waves), BK=64 dbuf, XOR-swizzled LDS.
// ---------------------------------------------------------------------------
__device__ __forceinline__ void l1_phase(
    ushort_t* Al0, ushort_t* Bl0,
    int m0, int i0, int i, int t,
    const int* __restrict__ tgt, const float* __restrict__ xe1,
    const ushort_t* __restrict__ rkt,
    float rbz, float rbr, float rbh,
    const ushort_t* __restrict__ hb_cur,
    __hip_bfloat16* __restrict__ hb_nxt,
    float (&hv)[2][4])
{
    const int tid  = threadIdx.x;
    const int lane = tid & 63;
    const int w    = tid >> 6;
    const int ln   = lane & 15;
    const int kg   = lane >> 4;
    const int wr   = w >> 1;

    const int crow = lane >> 3;
    const int ckof = ((lane & 7) ^ crow) * 8;

    int ids[2][4];
    #pragma unroll
    for (int fm = 0; fm < 2; ++fm)
        #pragma unroll
        for (int r = 0; r < 4; ++r) {
            const int b = m0 + wr * 32 + fm * 16 + kg * 4 + r;
            ids[fm][r] = tgt[(size_t)b * T_ + t];
        }
    float xgz[2][4], xgr[2][4], xgh[2][4];
    #pragma unroll
    for (int fm = 0; fm < 2; ++fm)
        #pragma unroll
        for (int r = 0; r < 4; ++r) {
            const float* xg = xe1 + (size_t)ids[fm][r] * H3_;
            xgz[fm][r] = xg[i]; xgr[fm][r] = xg[H_ + i]; xgh[fm][r] = xg[2 * H_ + i];
        }

    const int ko0 = (kg * 8) ^ ((ln & 7) * 8);
    const int ko1 = (32 + kg * 8) ^ ((ln & 7) * 8);

    f32x4 acc[2][3] = {};

    auto STAGE = [&](int pb, int k0) {
        #pragma unroll
        for (int c = w; c < 20; c += 4) {
            const ushort_t* g; ushort_t* l;
            if (c < 8) {
                g = hb_cur + (size_t)(m0 + c * 8 + crow) * H_ + k0 + ckof;
                l = Al0 + pb * 4096 + c * 512;
            } else {
                const int idx = c - 8;
                g = rkt + (size_t)((idx >> 2) * H_ + i0 + (idx & 3) * 8 + crow) * H_ + k0 + ckof;
                l = Bl0 + pb * 6144 + idx * 512;
            }
            stage16(g, l, lane);
        }
    };

    STAGE(0, 0);
    __syncthreads();
    int buf = 0;
    for (int k0 = 0; k0 < H_; k0 += 64) {
        if (k0 + 64 < H_) STAGE(buf ^ 1, k0 + 64);
        #pragma unroll
        for (int kk = 0; kk < 2; ++kk) {
            const int ko = kk ? ko1 : ko0;
            bf16x8 af[2], bf[3];
            #pragma unroll
            for (int fm = 0; fm < 2; ++fm)
                af[fm] = *(const bf16x8*)(Al0 + buf * 4096 + (wr * 32 + fm * 16 + ln) * 64 + ko);
            #pragma unroll
            for (int g = 0; g < 3; ++g)
                bf[g] = *(const bf16x8*)(Bl0 + buf * 6144 + g * 2048 + ((w & 1) * 16 + ln) * 64 + ko);
            #pragma unroll
            for (int fm = 0; fm < 2; ++fm)
                #pragma unroll
                for (int g = 0; g < 3; ++g)
                    acc[fm][g] = __builtin_amdgcn_mfma_f32_16x16x32_bf16(
                        af[fm], bf[g], acc[fm][g], 0, 0, 0);
        }
        __syncthreads();
        buf ^= 1;
    }

    #pragma unroll
    for (int fm = 0; fm < 2; ++fm)
        #pragma unroll
        for (int r = 0; r < 4; ++r) {
            const int b = m0 + wr * 32 + fm * 16 + kg * 4 + r;
            const float hvv = hv[fm][r];
            float z  = sigmoidf_(xgz[fm][r] + acc[fm][0][r] + rbz);
            float rr = sigmoidf_(xgr[fm][r] + acc[fm][1][r] + rbr);
            float hh = tanhf(xgh[fm][r] + rr * (acc[fm][2][r] + rbh));
            float hn = (ids[fm][r] != 0) ? (z * hvv + (1.0f - z) * hh) : hvv;
            hv[fm][r] = hn;
            hb_nxt[(size_t)b * H_ + i] = __float2bfloat16(hn);
        }
}

// ---------------------------------------------------------------------------
// Layer-2 phase body. fp32 carry in registers; A dbuf + B split-stage.
// lds: 28672 ushorts (56 KB).
// ---------------------------------------------------------------------------
__device__ __forceinline__ void l2_phase(
    ushort_t* lds,
    int m0, int i0, int i, int t,
    const int* __restrict__ tgt,
    const ushort_t* __restrict__ k2t, const ushort_t* __restrict__ rk2t,
    float bxz, float bxr, float bxh,
    float brz, float brr, float brh,
    const ushort_t* __restrict__ s1b,
    const ushort_t* __restrict__ a1, size_t a1s,
    __hip_bfloat16* __restrict__ hbo, size_t hos,
    float (&hv)[2][4])
{
    ushort_t* A0l = lds;            // 2 x 4096
    ushort_t* A1l = lds + 8192;     // 2 x 4096
    ushort_t* B0l = lds + 16384;    // 6144
    ushort_t* B1l = lds + 22528;    // 6144

    const int tid  = threadIdx.x;
    const int lane = tid & 63;
    const int w    = tid >> 6;
    const int ln   = lane & 15;
    const int kg   = lane >> 4;
    const int wr   = w >> 1;

    const int crow = lane >> 3;
    const int ckof = ((lane & 7) ^ crow) * 8;

    int ids[2][4];
    #pragma unroll
    for (int fm = 0; fm < 2; ++fm)
        #pragma unroll
        for (int r = 0; r < 4; ++r) {
            const int b = m0 + wr * 32 + fm * 16 + kg * 4 + r;
            ids[fm][r] = tgt[(size_t)b * T_ + t];
        }

    const int ko0 = (kg * 8) ^ ((ln & 7) * 8);
    const int ko1 = (32 + kg * 8) ^ ((ln & 7) * 8);

    auto STAGE_A = [&](int pb, int k0) {
        #pragma unroll
        for (int c = w; c < 16; c += 4) {
            const ushort_t* g; ushort_t* l;
            if (c < 8) {
                g = s1b + (size_t)(m0 + c * 8 + crow) * H_ + k0 + ckof;
                l = A0l + pb * 4096 + c * 512;
            } else {
                const int cc = c - 8;
                g = a1 + (size_t)(m0 + cc * 8 + crow) * a1s + k0 + ckof;
                l = A1l + pb * 4096 + cc * 512;
            }
            stage16(g, l, lane);
        }
    };
    auto STAGE_B = [&](int k0) {
        #pragma unroll
        for (int c = w; c < 24; c += 4) {
            const ushort_t* g; ushort_t* l;
            if (c < 12) {
                g = k2t + (size_t)((c >> 2) * H_ + i0 + (c & 3) * 8 + crow) * H_ + k0 + ckof;
                l = B0l + c * 512;
            } else {
                const int idx = c - 12;
                g = rk2t + (size_t)((idx >> 2) * H_ + i0 + (idx & 3) * 8 + crow) * H_ + k0 + ckof;
                l = B1l + idx * 512;
            }
            stage16(g, l, lane);
        }
    };

    f32x4 acc0[2][3] = {};
    f32x4 acc1[2][3] = {};

    STAGE_A(0, 0);
    STAGE_B(0);
    __syncthreads();
    int buf = 0;
    for (int k0 = 0; k0 < H_; k0 += 64) {
        const bool more = (k0 + 64 < H_);
        if (more) STAGE_A(buf ^ 1, k0 + 64);

        bf16x8 a0f[2][2], a1f[2][2], b0f[2][3], b1f[2][3];
        #pragma unroll
        for (int kk = 0; kk < 2; ++kk) {
            const int ko = kk ? ko1 : ko0;
            #pragma unroll
            for (int fm = 0; fm < 2; ++fm) {
                a0f[kk][fm] = *(const bf16x8*)(A0l + buf * 4096 + (wr * 32 + fm * 16 + ln) * 64 + ko);
                a1f[kk][fm] = *(const bf16x8*)(A1l + buf * 4096 + (wr * 32 + fm * 16 + ln) * 64 + ko);
            }
            #pragma unroll
            for (int g = 0; g < 3; ++g) {
                b0f[kk][g] = *(const bf16x8*)(B0l + g * 2048 + ((w & 1) * 16 + ln) * 64 + ko);
                b1f[kk][g] = *(const bf16x8*)(B1l + g * 2048 + ((w & 1) * 16 + ln) * 64 + ko);
            }
        }
        __builtin_amdgcn_sched_barrier(0);
        asm volatile("s_waitcnt lgkmcnt(0)" ::: "memory");
        __builtin_amdgcn_sched_barrier(0);
        __builtin_amdgcn_s_barrier();
        if (more) STAGE_B(k0 + 64);

        #pragma unroll
        for (int kk = 0; kk < 2; ++kk)
            #pragma unroll
            for (int fm = 0; fm < 2; ++fm)
                #pragma unroll
                for (int g = 0; g < 3; ++g) {
                    acc0[fm][g] = __builtin_amdgcn_mfma_f32_16x16x32_bf16(
                        a0f[kk][fm], b0f[kk][g], acc0[fm][g], 0, 0, 0);
                    acc1[fm][g] = __builtin_amdgcn_mfma_f32_16x16x32_bf16(
                        a1f[kk][fm], b1f[kk][g], acc1[fm][g], 0, 0, 0);
                }
        __syncthreads();
        buf ^= 1;
    }

    #pragma unroll
    for (int fm = 0; fm < 2; ++fm)
        #pragma unroll
        for (int r = 0; r < 4; ++r) {
            const int b = m0 + wr * 32 + fm * 16 + kg * 4 + r;
            const float hvv = hv[fm][r];
            float z  = sigmoidf_((acc0[fm][0][r] + bxz) + (acc1[fm][0][r] + brz));
            float rr = sigmoidf_((acc0[fm][1][r] + bxr) + (acc1[fm][1][r] + brr));
            float hh = tanhf((acc0[fm][2][r] + bxh) + rr * (acc1[fm][2][r] + brh));
            float hn = (ids[fm][r] != 0) ? (z * hvv + (1.0f - z) * hh) : hvv;
            hv[fm][r] = hn;
            hbo[(size_t)b * hos + i] = __float2bfloat16(hn);
        }
}

// ---------------------------------------------------------------------------
// Standalone per-step wrappers (fallback path): global fp32 carry.
// ---------------------------------------------------------------------------
__global__ __launch_bounds__(256, 2) void l1_fused(
    const int* __restrict__ tgt, int t,
    const float* __restrict__ xe1, const ushort_t* __restrict__ rkt,
    const float* __restrict__ rb,
    const float* __restrict__ hf_cur, const ushort_t* __restrict__ hb_cur,
    float* __restrict__ hf_nxt, __hip_bfloat16* __restrict__ hb_nxt)
{
    __shared__ __attribute__((aligned(16))) ushort_t lds[20480];
    int m0, i0; tile_map(blockIdx.x, m0, i0);
    const int tid = threadIdx.x, lane = tid & 63, w = tid >> 6;
    const int ln = lane & 15, kg = lane >> 4, wr = w >> 1, wc = w & 1;
    const int i = i0 + wc * 16 + ln;

    float hv[2][4];
    #pragma unroll
    for (int fm = 0; fm < 2; ++fm)
        #pragma unroll
        for (int r = 0; r < 4; ++r)
            hv[fm][r] = hf_cur[(size_t)(m0 + wr * 32 + fm * 16 + kg * 4 + r) * H_ + i];

    l1_phase(lds, lds + 8192, m0, i0, i, t, tgt, xe1, rkt,
             rb[i], rb[H_ + i], rb[2 * H_ + i], hb_cur, hb_nxt, hv);

    #pragma unroll
    for (int fm = 0; fm < 2; ++fm)
        #pragma unroll
        for (int r = 0; r < 4; ++r)
            hf_nxt[(size_t)(m0 + wr * 32 + fm * 16 + kg * 4 + r) * H_ + i] = hv[fm][r];
}

__global__ __launch_bounds__(256, 2) void l2_fused(
    const int* __restrict__ tgt, int t,
    const ushort_t* __restrict__ k2t, const ushort_t* __restrict__ rk2t,
    const float* __restrict__ bx, const float* __restrict__ br,
    const ushort_t* __restrict__ s1b,
    const float* __restrict__ hf_cur,
    const ushort_t* __restrict__ hb_cur, size_t hbs,
    float* __restrict__ hf_nxt,
    __hip_bfloat16* __restrict__ hbo, size_t hos)
{
    __shared__ __attribute__((aligned(16))) ushort_t lds[28672];
    int m0, i0; tile_map(blockIdx.x, m0, i0);
    const int tid = threadIdx.x, lane = tid & 63, w = tid >> 6;
    const int ln = lane & 15, kg = lane >> 4, wr = w >> 1, wc = w & 1;
    const int i = i0 + wc * 16 + ln;

    float hv[2][4];
    #pragma unroll
    for (int fm = 0; fm < 2; ++fm)
        #pragma unroll
        for (int r = 0; r < 4; ++r)
            hv[fm][r] = hf_cur[(size_t)(m0 + wr * 32 + fm * 16 + kg * 4 + r) * H_ + i];

    l2_phase(lds, m0, i0, i, t, tgt, k2t, rk2t,
             bx[i], bx[H_ + i], bx[2 * H_ + i],
             br[i], br[H_ + i], br[2 * H_ + i],
             s1b, hb_cur, hbs, hbo, hos, hv);

    #pragma unroll
    for (int fm = 0; fm < 2; ++fm)
        #pragma unroll
        for (int r = 0; r < 4; ++r)
            hf_nxt[(size_t)(m0 + wr * 32 + fm * 16 + kg * 4 + r) * H_ + i] = hv[fm][r];
}

// ---------------------------------------------------------------------------
// Grid barrier, monotonic counter, RELAXED spin (no per-poll cache inval).
// One release fence before arrival, one acquire fence after the flag flips.
// ---------------------------------------------------------------------------
__device__ __forceinline__ void grid_barrier(unsigned* bar, unsigned phase)
{
    __syncthreads();
    if (threadIdx.x == 0) {
        __builtin_amdgcn_fence(__ATOMIC_RELEASE, "agent");
        const unsigned arrived =
            __hip_atomic_fetch_add(&bar[0], 1u, __ATOMIC_RELAXED, __HIP_MEMORY_SCOPE_AGENT) + 1u;
        if (arrived == (unsigned)NBLK_ * (phase + 1u)) {
            __hip_atomic_store(&bar[1], phase + 1u, __ATOMIC_RELAXED, __HIP_MEMORY_SCOPE_AGENT);
        } else {
            while (__hip_atomic_load(&bar[1], __ATOMIC_RELAXED, __HIP_MEMORY_SCOPE_AGENT) < phase + 1u)
                __builtin_amdgcn_s_sleep(4);
        }
        __builtin_amdgcn_fence(__ATOMIC_ACQUIRE, "agent");
    }
    __syncthreads();
}

// ---------------------------------------------------------------------------
// Persistent recurrence: r5 structure (separate l1/l2 phases, 2 barriers per
// step) + register fp32 carry + relaxed barrier. 95 barriers total.
// ---------------------------------------------------------------------------
__global__ __launch_bounds__(256, 2) void recurrence_all(
    const int* __restrict__ tgt, const float* __restrict__ xe1,
    const ushort_t* __restrict__ rk1t, const float* __restrict__ rb1,
    const ushort_t* __restrict__ k2t, const ushort_t* __restrict__ rk2t,
    const float* __restrict__ bx, const float* __restrict__ br,
    const float* __restrict__ h1f0, __hip_bfloat16* __restrict__ h1b,
    const float* __restrict__ h2f0, const __hip_bfloat16* __restrict__ h2b0,
    __hip_bfloat16* __restrict__ seq2b, unsigned* __restrict__ bar)
{
    __shared__ __attribute__((aligned(16))) ushort_t lds[28672];  // 56 KB
    int m0, i0; tile_map(blockIdx.x, m0, i0);
    const int tid = threadIdx.x, lane = tid & 63, w = tid >> 6;
    const int ln = lane & 15, kg = lane >> 4, wr = w >> 1, wc = w & 1;
    const int i = i0 + wc * 16 + ln;

    const float rbz = rb1[i], rbr = rb1[H_ + i], rbh = rb1[2 * H_ + i];
    const float bxz = bx[i],  bxr = bx[H_ + i],  bxh = bx[2 * H_ + i];
    const float brz = br[i],  brr = br[H_ + i],  brh = br[2 * H_ + i];

    float hv1[2][4], hv2[2][4];
    #pragma unroll
    for (int fm = 0; fm < 2; ++fm)
        #pragma unroll
        for (int r = 0; r < 4; ++r) {
            const size_t b = (size_t)(m0 + wr * 32 + fm * 16 + kg * 4 + r) * H_ + i;
            hv1[fm][r] = h1f0[b];
            hv2[fm][r] = h2f0[b];
        }

    unsigned ph = 0;

    #pragma unroll 1
    for (int t = 0; t < T_; ++t) {
        const int cur = t & 1, nxt = cur ^ 1;

        l1_phase(lds, lds + 8192, m0, i0, i, t, tgt, xe1, rk1t,
                 rbz, rbr, rbh,
                 (const ushort_t*)(h1b + (size_t)cur * BH_),
                 h1b + (size_t)nxt * BH_, hv1);
        grid_barrier(bar, ph); ++ph;

        const ushort_t* a1 = (t == 0)
            ? (const ushort_t*)h2b0
            : (const ushort_t*)(seq2b + (size_t)(t - 1) * H_);
        const size_t a1s = (t == 0) ? (size_t)H_ : (size_t)T_ * H_;

        l2_phase(lds, m0, i0, i, t, tgt, k2t, rk2t,
                 bxz, bxr, bxh, brz, brr, brh,
                 (const ushort_t*)(h1b + (size_t)nxt * BH_),
                 a1, a1s,
                 seq2b + (size_t)t * H_, (size_t)T_ * H_, hv2);
        if (t + 1 < T_) { grid_barrier(bar, ph); ++ph; }
    }
}

// ---------------------------------------------------------------------------
// Softmax helpers + per-step fallback kernel (small-workspace path)
// ---------------------------------------------------------------------------
__device__ __forceinline__ void softmax_write4(
    float ax, float ay, float az, float aw, float* __restrict__ outp, int cg)
{
    float m = fmaxf(fmaxf(ax, ay), fmaxf(az, aw));
    #pragma unroll
    for (int d = 16; d >= 1; d >>= 1) m = fmaxf(m, __shfl_xor(m, d));
    float ex = __expf(ax - m), ey = __expf(ay - m),
          ez = __expf(az - m), ew = __expf(aw - m);
    float s = ex + ey + ez + ew;
    #pragma unroll
    for (int d = 16; d >= 1; d >>= 1) s += __shfl_xor(s, d);
    float inv = 1.0f / s;
    float4 o; o.x = ex * inv; o.y = ey * inv; o.z = ez * inv; o.w = ew * inv;
    *(float4*)(outp + cg * 4) = o;
}

__global__ __launch_bounds__(256) void out_softmax(
    const float* __restrict__ h2, const float* __restrict__ Wv,
    const float* __restrict__ bv, float* __restrict__ out, int t)
{
    const int tid = threadIdx.x;
    const int cg = tid & 31;
    const int rg = tid >> 5;
    const int row0 = blockIdx.x * 16;

    __shared__ float hs[16][512];
    for (int idx = tid; idx < 16 * 512; idx += 256)
        hs[idx >> 9][idx & 511] = h2[(size_t)(row0 + (idx >> 9)) * 512 + (idx & 511)];
    __syncthreads();

    const int r0 = rg * 2;
    const float4 bvv = *(const float4*)(bv + cg * 4);
    float a0x = bvv.x, a0y = bvv.y, a0z = bvv.z, a0w = bvv.w;
    float a1x = bvv.x, a1y = bvv.y, a1z = bvv.z, a1w = bvv.w;

    #pragma unroll 4
    for (int k = 0; k < 512; ++k) {
        float4 wv = *(const float4*)(Wv + (size_t)k * V_ + cg * 4);
        float h0 = hs[r0][k], h1 = hs[r0 + 1][k];
        a0x += h0 * wv.x; a0y += h0 * wv.y; a0z += h0 * wv.z; a0w += h0 * wv.w;
        a1x += h1 * wv.x; a1y += h1 * wv.y; a1z += h1 * wv.z; a1w += h1 * wv.w;
    }

    softmax_write4(a0x, a0y, a0z, a0w, out + ((size_t)(row0 + r0) * T_ + t) * V_, cg);
    softmax_write4(a1x, a1y, a1z, a1w, out + ((size_t)(row0 + r0 + 1) * T_ + t) * V_, cg);
}

// ---------------------------------------------------------------------------
// Batched MFMA vocab projection + softmax (off critical path).
// ---------------------------------------------------------------------------
__global__ __launch_bounds__(256) void proj_mfma(
    const ushort_t* __restrict__ s2, const ushort_t* __restrict__ wvt,
    const float* __restrict__ bv, float* __restrict__ out)
{
    const int lane = threadIdx.x & 63;
    const int w    = threadIdx.x >> 6;
    const int ln   = lane & 15;
    const int kg   = lane >> 4;
    const size_t row0 = (size_t)blockIdx.x * 128 + (size_t)w * 32;

    float bvl[8];
    #pragma unroll
    for (int nf = 0; nf < 8; ++nf) bvl[nf] = bv[nf * 16 + ln];

    f32x4 acc[2][8] = {};
    #pragma unroll 2
    for (int k0 = 0; k0 < H_; k0 += 32) {
        bf16x8 af[2], bf[8];
        #pragma unroll
        for (int mf = 0; mf < 2; ++mf)
            af[mf] = *(const bf16x8*)(s2 + (row0 + mf * 16 + ln) * H_ + k0 + kg * 8);
        #pragma unroll
        for (int nf = 0; nf < 8; ++nf)
            bf[nf] = *(const bf16x8*)(wvt + (size_t)(nf * 16 + ln) * H_ + k0 + kg * 8);
        #pragma unroll
        for (int mf = 0; mf < 2; ++mf)
            #pragma unroll
            for (int nf = 0; nf < 8; ++nf)
                acc[mf][nf] = __builtin_amdgcn_mfma_f32_16x16x32_bf16(
                    af[mf], bf[nf], acc[mf][nf], 0, 0, 0);
    }

    #pragma unroll
    for (int mf = 0; mf < 2; ++mf)
        #pragma unroll
        for (int q = 0; q < 4; ++q) {
            float v[8];
            float m = -1e30f;
            #pragma unroll
            for (int nf = 0; nf < 8; ++nf) { v[nf] = acc[mf][nf][q] + bvl[nf]; m = fmaxf(m, v[nf]); }
            #pragma unroll
            for (int d = 1; d <= 8; d <<= 1) m = fmaxf(m, __shfl_xor(m, d));
            float s = 0.f;
            #pragma unroll
            for (int nf = 0; nf < 8; ++nf) { v[nf] = __expf(v[nf] - m); s += v[nf]; }
            #pragma unroll
            for (int d = 1; d <= 8; d <<= 1) s += __shfl_xor(s, d);
            const float inv = 1.0f / s;
            float* op = out + (row0 + mf * 16 + kg * 4 + q) * V_;
            #pragma unroll
            for (int nf = 0; nf < 8; ++nf) op[nf * 16 + ln] = v[nf] * inv;
        }
}

// ---------------------------------------------------------------------------
// Launch
// ---------------------------------------------------------------------------
extern "C" void kernel_launch(void* const* d_in, const int* in_sizes, int n_in,
                              void* d_out, int out_size, void* d_ws, size_t ws_size,
                              hipStream_t stream)
{
    const int*   tgt  = (const int*)  d_in[0];
    const float* enc  = (const float*)d_in[1];
    const float* Wi1  = (const float*)d_in[2];
    const float* Wi2  = (const float*)d_in[3];
    const float* emb  = (const float*)d_in[4];
    const float* k1   = (const float*)d_in[5];
    const float* rk1  = (const float*)d_in[6];
    const float* b1   = (const float*)d_in[7];
    const float* k2   = (const float*)d_in[8];
    const float* rk2  = (const float*)d_in[9];
    const float* b2   = (const float*)d_in[10];
    const float* Wv   = (const float*)d_in[11];
    const float* bv   = (const float*)d_in[12];
    float* out = (float*)d_out;

    // workspace layout
    float* ws  = (float*)d_ws;
    float* xe1 = ws;                                   // [V,3H] f32
    float* h1f = xe1 + (size_t)V_ * H3_;               // [2][B*H] f32
    float* h2f = h1f + (size_t)2 * BH_;                // [2][B*H] f32
    __hip_bfloat16* h1b = (__hip_bfloat16*)(h2f + (size_t)2 * BH_);  // [2][B*H]
    __hip_bfloat16* h2b = h1b + (size_t)2 * BH_;       // [2][B*H]
    __hip_bfloat16* rk1t = h2b + (size_t)2 * BH_;      // [3H,H]
    __hip_bfloat16* k2t  = rk1t + (size_t)H3_ * H_;
    __hip_bfloat16* rk2t = k2t  + (size_t)H3_ * H_;
    __hip_bfloat16* wvt  = rk2t + (size_t)H3_ * H_;    // [V,H]
    __hip_bfloat16* ehi  = wvt + (size_t)V_ * H_;      // [B,ENC]
    __hip_bfloat16* elo  = ehi + (size_t)B_ * ENC_;
    __hip_bfloat16* w1hi = elo + (size_t)B_ * ENC_;    // [H,ENC] x4
    __hip_bfloat16* w1lo = w1hi + (size_t)H_ * ENC_;
    __hip_bfloat16* w2hi = w1lo + (size_t)H_ * ENC_;
    __hip_bfloat16* w2lo = w2hi + (size_t)H_ * ENC_;
    __hip_bfloat16* seq2b = w2lo + (size_t)H_ * ENC_;  // [B,T,H] bf16
    unsigned* bar = (unsigned*)(seq2b + (size_t)B_ * T_ * H_);  // 64 B

    const size_t need = (size_t)((char*)bar + 64 - (char*)d_ws);
    const bool batched = ws_size >= need;

    static int persist_state = -1;
    if (persist_state < 0) {
        int nb = 0;
        hipError_t e1 = hipOccupancyMaxActiveBlocksPerMultiprocessor(&nb, recurrence_all, 256, 0);
        hipDeviceProp_t prop;
        hipError_t e2 = hipGetDeviceProperties(&prop, 0);
        persist_state = (e1 == hipSuccess && e2 == hipSuccess &&
                         (long)nb * prop.multiProcessorCount >= NBLK_) ? 1 : 0;
    }
    const bool persist = batched && persist_state == 1;

    dim3 blk(256);

    // one-time: weight transposes to bf16
    transpose_to_bf16<<<dim3(H3_ / 32, H_ / 32), blk, 0, stream>>>(rk1, rk1t, H_, H3_);
    transpose_to_bf16<<<dim3(H3_ / 32, H_ / 32), blk, 0, stream>>>(k2,  k2t,  H_, H3_);
    transpose_to_bf16<<<dim3(H3_ / 32, H_ / 32), blk, 0, stream>>>(rk2, rk2t, H_, H3_);
    if (batched)
        transpose_to_bf16<<<dim3(V_ / 32, H_ / 32), blk, 0, stream>>>(Wv, wvt, H_, V_);

    // split-bf16 operands for the exact MFMA h0-init
    split_cast<<<dim3((B_ * ENC_) / 1024), blk, 0, stream>>>(enc, ehi, elo, B_ * ENC_);
    transpose_split<<<dim3(H_ / 32, ENC_ / 32), blk, 0, stream>>>(Wi1, w1hi, w1lo, ENC_, H_);
    transpose_split<<<dim3(H_ / 32, ENC_ / 32), blk, 0, stream>>>(Wi2, w2hi, w2lo, ENC_, H_);

    // xe1 = embed_table @ k1 + b1[0]  (fp32, exact)
    gemm_f32<<<dim3(H3_ / BN, V_ / BM), blk, 0, stream>>>(emb, k1, b1, xe1, V_, H3_, E_);

    // h0-init
    init_mfma<<<dim3(H_ / 32, B_ / 64, 2), blk, 0, stream>>>(
        (const ushort_t*)ehi, (const ushort_t*)elo,
        (const ushort_t*)w1hi, (const ushort_t*)w1lo,
        (const ushort_t*)w2hi, (const ushort_t*)w2lo,
        h1f, h1b, h2f, h2b);

    if (persist) {
        hipMemsetAsync(bar, 0, 64, stream);
        recurrence_all<<<dim3(NBLK_), blk, 0, stream>>>(
            tgt, xe1, (const ushort_t*)rk1t, b1 + H3_,
            (const ushort_t*)k2t, (const ushort_t*)rk2t, b2, b2 + H3_,
            h1f, h1b, h2f, h2b, seq2b, bar);
        proj_mfma<<<dim3((B_ * T_) / 128), blk, 0, stream>>>(
            (const ushort_t*)seq2b, (const ushort_t*)wvt, bv, out);
        return;
    }

    // fallback: per-step launches
    const dim3 fgrid(NBLK_);
    for (int t = 0; t < T_; ++t) {
        const int cur = t & 1, nxt = cur ^ 1;
        float* h1f_c = h1f + (size_t)cur * BH_;
        float* h1f_n = h1f + (size_t)nxt * BH_;
        float* h2f_c = h2f + (size_t)cur * BH_;
        float* h2f_n = h2f + (size_t)nxt * BH_;
        __hip_bfloat16* h1b_c = h1b + (size_t)cur * BH_;
        __hip_bfloat16* h1b_n = h1b + (size_t)nxt * BH_;

        l1_fused<<<fgrid, blk, 0, stream>>>(
            tgt, t, xe1, (const ushort_t*)rk1t, b1 + H3_,
            h1f_c, (const ushort_t*)h1b_c, h1f_n, h1b_n);

        const ushort_t* hb_c; size_t hbs;
        __hip_bfloat16* hbo; size_t hos;
        if (batched) {
            hb_c = (t == 0) ? (const ushort_t*)h2b
                            : (const ushort_t*)(seq2b + (size_t)(t - 1) * H_);
            hbs  = (t == 0) ? (size_t)H_ : (size_t)T_ * H_;
            hbo  = seq2b + (size_t)t * H_;
            hos  = (size_t)T_ * H_;
        } else {
            hb_c = (const ushort_t*)(h2b + (size_t)cur * BH_); hbs = H_;
            hbo  = h2b + (size_t)nxt * BH_;                    hos = H_;
        }

        l2_fused<<<fgrid, blk, 0, stream>>>(
            tgt, t, (const ushort_t*)k2t, (const ushort_t*)rk2t, b2, b2 + H3_,
            (const ushort_t*)h1b_n, h2f_c, hb_c, hbs, h2f_n, hbo, hos);

        if (!batched)
            out_softmax<<<dim3(B_ / 16), blk, 0, stream>>>(h2f_n, Wv, bv, out, t);
    }

    if (batched)
        proj_mfma<<<dim3((B_ * T_) / 128), blk, 0, stream>>>(
            (const ushort_t*)seq2b, (const ushort_t*)wvt, bv, out);
}

// Round 10
// 1435.111 us; speedup vs baseline: 1.2665x; 1.0554x over previous
//
#include <hip/hip_runtime.h>
#include <hip/hip_bf16.h>
#include <math.h>

// Problem constants
#define B_   2048
#define T_   48
#define H_   512
#define E_   256
#define V_   128
#define ENC_ 1024
#define H3_  1536   // 3*H
#define BH_  (B_ * H_)
#define NBLK_ 512   // persistent grid size (2 blocks/CU on 256 CUs)

typedef __attribute__((ext_vector_type(8))) short bf16x8;   // 8 bf16 = 4 VGPRs
typedef __attribute__((ext_vector_type(4))) float f32x4;
typedef unsigned short ushort_t;

#if defined(__has_builtin)
#if __has_builtin(__builtin_amdgcn_global_load_lds)
#define HAVE_ASYNC 1
#endif
#endif
#ifndef HAVE_ASYNC
#define HAVE_ASYNC 0
#endif

__device__ __forceinline__ void stage16(const ushort_t* g, ushort_t* l, int lane)
{
#if HAVE_ASYNC
    __builtin_amdgcn_global_load_lds(
        (const __attribute__((address_space(1))) unsigned int*)g,
        (__attribute__((address_space(3))) unsigned int*)l, 16, 0, 0);
#else
    *(bf16x8*)(l + lane * 8) = *(const bf16x8*)g;
#endif
}

// Coherent (device/system-scope) 16B load: bypasses the non-coherent per-XCD
// L2, served by the shared memory-side Infinity Cache. Used ONLY for state.
__device__ __forceinline__ bf16x8 load16_sc(const ushort_t* g)
{
    bf16x8 r;
    asm volatile("global_load_dwordx4 %0, %1, off sc0 sc1" : "=v"(r) : "v"(g));
    return r;
}

// Coherent bf16 store (write-through past L2 to the device coherence point).
__device__ __forceinline__ void store_bf16_sc(__hip_bfloat16* p, float v)
{
    union { __hip_bfloat16 h; unsigned short u; } cv;
    cv.h = __float2bfloat16(v);
    unsigned uv = cv.u;
    asm volatile("global_store_short %0, %1, off sc0 sc1" :: "v"(p), "v"(uv) : "memory");
}

// Counted waits for the asm state-loads (compiler can't track them).
__device__ __forceinline__ void wait_vm3()
{ asm volatile("s_waitcnt vmcnt(3)" ::: "memory"); __builtin_amdgcn_sched_barrier(0); }
__device__ __forceinline__ void wait_vm6()
{ asm volatile("s_waitcnt vmcnt(6)" ::: "memory"); __builtin_amdgcn_sched_barrier(0); }

__device__ __forceinline__ float sigmoidf_(float x) { return 1.0f / (1.0f + expf(-x)); }

// i0-pinned tile map: XCD (lin&7 under round-robin dispatch) owns 2 i-slices
// -> its weight working set (~0.6 MB) stays L2-resident across all steps
// (the barrier no longer invalidates L2). State bypasses L2 via sc loads.
__device__ __forceinline__ void tile_map(int lin, int& m0, int& i0)
{
    i0 = ((((lin & 7) << 1) | ((lin >> 3) & 1))) * 32;
    m0 = (lin >> 4) * 64;
}

// ---------------------------------------------------------------------------
// fp32 tiled GEMM (xe1 setup only)
// ---------------------------------------------------------------------------
constexpr int BM = 64, BN = 64, BK = 16;

__global__ __launch_bounds__(256) void gemm_f32(
    const float* __restrict__ A, const float* __restrict__ Bm,
    const float* __restrict__ bias, float* __restrict__ C,
    int M, int N, int K)
{
    __shared__ float As[BK][BM + 4];
    __shared__ float Bs[BK][BN + 4];

    const int tid = threadIdx.x;
    const int bm = blockIdx.y * BM;
    const int bn = blockIdx.x * BN;
    const int tm = (tid >> 4) * 4;
    const int tn = (tid & 15) * 4;
    const int lmA = tid >> 2;
    const int lkA = (tid & 3) * 4;
    const int lkB = tid >> 4;
    const int lnB = (tid & 15) * 4;

    float acc[4][4] = {};

    for (int k0 = 0; k0 < K; k0 += BK) {
        float4 av  = *(const float4*)(A  + (size_t)(bm + lmA) * K + (k0 + lkA));
        float4 bv4 = *(const float4*)(Bm + (size_t)(k0 + lkB) * N + (bn + lnB));
        As[lkA + 0][lmA] = av.x;
        As[lkA + 1][lmA] = av.y;
        As[lkA + 2][lmA] = av.z;
        As[lkA + 3][lmA] = av.w;
        *(float4*)&Bs[lkB][lnB] = bv4;
        __syncthreads();

        #pragma unroll
        for (int k = 0; k < BK; ++k) {
            float4 a = *(const float4*)&As[k][tm];
            float4 b = *(const float4*)&Bs[k][tn];
            acc[0][0] += a.x * b.x; acc[0][1] += a.x * b.y; acc[0][2] += a.x * b.z; acc[0][3] += a.x * b.w;
            acc[1][0] += a.y * b.x; acc[1][1] += a.y * b.y; acc[1][2] += a.y * b.z; acc[1][3] += a.y * b.w;
            acc[2][0] += a.z * b.x; acc[2][1] += a.z * b.y; acc[2][2] += a.z * b.z; acc[2][3] += a.z * b.w;
            acc[3][0] += a.w * b.x; acc[3][1] += a.w * b.y; acc[3][2] += a.w * b.z; acc[3][3] += a.w * b.w;
        }
        __syncthreads();
    }

    #pragma unroll
    for (int r = 0; r < 4; ++r)
        #pragma unroll
        for (int c = 0; c < 4; ++c) {
            float v = acc[r][c];
            if (bias) v += bias[bn + tn + c];
            C[(size_t)(bm + tm + r) * N + (bn + tn + c)] = v;
        }
}

// ---------------------------------------------------------------------------
// Weight transpose + bf16 convert (one-time)
// ---------------------------------------------------------------------------
__global__ __launch_bounds__(256) void transpose_to_bf16(
    const float* __restrict__ W, __hip_bfloat16* __restrict__ Wt, int K, int N)
{
    __shared__ float tile[32][33];
    const int bk = blockIdx.y * 32, bn = blockIdx.x * 32;
    const int tx = threadIdx.x & 31, ty = threadIdx.x >> 5;
    #pragma unroll
    for (int i = ty; i < 32; i += 8)
        tile[i][tx] = W[(size_t)(bk + i) * N + (bn + tx)];
    __syncthreads();
    #pragma unroll
    for (int i = ty; i < 32; i += 8)
        Wt[(size_t)(bn + i) * K + (bk + tx)] = __float2bfloat16(tile[tx][i]);
}

__global__ __launch_bounds__(256) void transpose_split(
    const float* __restrict__ W, __hip_bfloat16* __restrict__ Whi,
    __hip_bfloat16* __restrict__ Wlo, int K, int N)
{
    __shared__ float tile[32][33];
    const int bk = blockIdx.y * 32, bn = blockIdx.x * 32;
    const int tx = threadIdx.x & 31, ty = threadIdx.x >> 5;
    #pragma unroll
    for (int i = ty; i < 32; i += 8)
        tile[i][tx] = W[(size_t)(bk + i) * N + (bn + tx)];
    __syncthreads();
    #pragma unroll
    for (int i = ty; i < 32; i += 8) {
        const float v = tile[tx][i];
        const __hip_bfloat16 h = __float2bfloat16(v);
        Whi[(size_t)(bn + i) * K + (bk + tx)] = h;
        Wlo[(size_t)(bn + i) * K + (bk + tx)] = __float2bfloat16(v - __bfloat162float(h));
    }
}

__global__ __launch_bounds__(256) void split_cast(
    const float* __restrict__ x, __hip_bfloat16* __restrict__ hi,
    __hip_bfloat16* __restrict__ lo, int n)
{
    const int i0 = (blockIdx.x * 256 + threadIdx.x) * 4;
    if (i0 >= n) return;
    const float4 v = *(const float4*)(x + i0);
    const float vv[4] = { v.x, v.y, v.z, v.w };
    #pragma unroll
    for (int j = 0; j < 4; ++j) {
        const __hip_bfloat16 h = __float2bfloat16(vv[j]);
        hi[i0 + j] = h;
        lo[i0 + j] = __float2bfloat16(vv[j] - __bfloat162float(h));
    }
}

// ---------------------------------------------------------------------------
// Exact-ish MFMA h0 init: C = ehi@Whi^T + elo@Whi^T + ehi@Wlo^T  (K=1024).
// ---------------------------------------------------------------------------
__global__ __launch_bounds__(256, 2) void init_mfma(
    const ushort_t* __restrict__ ehi, const ushort_t* __restrict__ elo,
    const ushort_t* __restrict__ w1hi, const ushort_t* __restrict__ w1lo,
    const ushort_t* __restrict__ w2hi, const ushort_t* __restrict__ w2lo,
    float* __restrict__ h1f, __hip_bfloat16* __restrict__ h1b,
    float* __restrict__ h2f, __hip_bfloat16* __restrict__ h2b)
{
    const ushort_t* whi = blockIdx.z ? w2hi : w1hi;
    const ushort_t* wlo = blockIdx.z ? w2lo : w1lo;
    float* hf = blockIdx.z ? h2f : h1f;
    __hip_bfloat16* hb = blockIdx.z ? h2b : h1b;

    __shared__ __attribute__((aligned(16))) ushort_t Ahi[2][4096];
    __shared__ __attribute__((aligned(16))) ushort_t Alo[2][4096];
    __shared__ __attribute__((aligned(16))) ushort_t Bhi[2][2048];
    __shared__ __attribute__((aligned(16))) ushort_t Blo[2][2048];

    const int tid  = threadIdx.x;
    const int lane = tid & 63;
    const int w    = tid >> 6;
    const int ln   = lane & 15;
    const int kg   = lane >> 4;
    const int wr   = w >> 1, wc = w & 1;
    const int m0   = blockIdx.y * 64;
    const int i0   = blockIdx.x * 32;

    const int crow = lane >> 3;
    const int ckof = ((lane & 7) ^ crow) * 8;
    const int ko0 = (kg * 8) ^ ((ln & 7) * 8);
    const int ko1 = (32 + kg * 8) ^ ((ln & 7) * 8);

    auto STG = [&](int pb, int k0) {
        #pragma unroll
        for (int c = w; c < 24; c += 4) {
            const ushort_t* g; ushort_t* l;
            if (c < 8) {
                g = ehi + (size_t)(m0 + c * 8 + crow) * ENC_ + k0 + ckof;
                l = &Ahi[pb][c * 512];
            } else if (c < 16) {
                const int cc = c - 8;
                g = elo + (size_t)(m0 + cc * 8 + crow) * ENC_ + k0 + ckof;
                l = &Alo[pb][cc * 512];
            } else if (c < 20) {
                const int cc = c - 16;
                g = whi + (size_t)(i0 + cc * 8 + crow) * ENC_ + k0 + ckof;
                l = &Bhi[pb][cc * 512];
            } else {
                const int cc = c - 20;
                g = wlo + (size_t)(i0 + cc * 8 + crow) * ENC_ + k0 + ckof;
                l = &Blo[pb][cc * 512];
            }
            stage16(g, l, lane);
        }
    };

    f32x4 acc[2] = {};
    STG(0, 0);
    __syncthreads();
    int buf = 0;
    for (int k0 = 0; k0 < ENC_; k0 += 64) {
        if (k0 + 64 < ENC_) STG(buf ^ 1, k0 + 64);
        #pragma unroll
        for (int kk = 0; kk < 2; ++kk) {
            const int ko = kk ? ko1 : ko0;
            bf16x8 ah[2], al[2], bh, bl;
            #pragma unroll
            for (int fm = 0; fm < 2; ++fm) {
                ah[fm] = *(const bf16x8*)(&Ahi[buf][(wr * 32 + fm * 16 + ln) * 64 + ko]);
                al[fm] = *(const bf16x8*)(&Alo[buf][(wr * 32 + fm * 16 + ln) * 64 + ko]);
            }
            bh = *(const bf16x8*)(&Bhi[buf][(wc * 16 + ln) * 64 + ko]);
            bl = *(const bf16x8*)(&Blo[buf][(wc * 16 + ln) * 64 + ko]);
            #pragma unroll
            for (int fm = 0; fm < 2; ++fm) {
                acc[fm] = __builtin_amdgcn_mfma_f32_16x16x32_bf16(ah[fm], bh, acc[fm], 0, 0, 0);
                acc[fm] = __builtin_amdgcn_mfma_f32_16x16x32_bf16(al[fm], bh, acc[fm], 0, 0, 0);
                acc[fm] = __builtin_amdgcn_mfma_f32_16x16x32_bf16(ah[fm], bl, acc[fm], 0, 0, 0);
            }
        }
        __syncthreads();
        buf ^= 1;
    }

    const int i = i0 + wc * 16 + ln;
    #pragma unroll
    for (int fm = 0; fm < 2; ++fm)
        #pragma unroll
        for (int r = 0; r < 4; ++r) {
            const int b = m0 + wr * 32 + fm * 16 + kg * 4 + r;
            const float v = acc[fm][r];
            hf[(size_t)b * H_ + i] = v;
            hb[(size_t)b * H_ + i] = __float2bfloat16(v);
        }
}

// ---------------------------------------------------------------------------
// Layer-1 phase body. State A-tile reg-staged via coherent sc-loads (bypass
// L2), weights via cached global_load_lds (L2-resident, never invalidated).
// fp32 carry in registers. 256 threads, BK=64 dbuf, XOR-swizzled LDS.
// ---------------------------------------------------------------------------
__device__ __forceinline__ void l1_phase(
    ushort_t* Al0, ushort_t* Bl0,
    int m0, int i0, int i, int t,
    const int* __restrict__ tgt, const float* __restrict__ xe1,
    const ushort_t* __restrict__ rkt,
    float rbz, float rbr, float rbh,
    const ushort_t* __restrict__ hb_cur,
    __hip_bfloat16* __restrict__ hb_nxt,
    float (&hv)[2][4])
{
    const int tid  = threadIdx.x;
    const int lane = tid & 63;
    const int w    = tid >> 6;
    const int ln   = lane & 15;
    const int kg   = lane >> 4;
    const int wr   = w >> 1;

    const int crow = lane >> 3;
    const int ckof = ((lane & 7) ^ crow) * 8;

    int ids[2][4];
    #pragma unroll
    for (int fm = 0; fm < 2; ++fm)
        #pragma unroll
        for (int r = 0; r < 4; ++r) {
            const int b = m0 + wr * 32 + fm * 16 + kg * 4 + r;
            ids[fm][r] = tgt[(size_t)b * T_ + t];
        }
    float xgz[2][4], xgr[2][4], xgh[2][4];
    #pragma unroll
    for (int fm = 0; fm < 2; ++fm)
        #pragma unroll
        for (int r = 0; r < 4; ++r) {
            const float* xg = xe1 + (size_t)ids[fm][r] * H3_;
            xgz[fm][r] = xg[i]; xgr[fm][r] = xg[H_ + i]; xgh[fm][r] = xg[2 * H_ + i];
        }

    const int ko0 = (kg * 8) ^ ((ln & 7) * 8);
    const int ko1 = (32 + kg * 8) ^ ((ln & 7) * 8);

    f32x4 acc[2][3] = {};
    bf16x8 areg[2];

    auto LOAD_A = [&](int k0) {     // 2 coherent loads/wave (8 chunks total)
        #pragma unroll
        for (int c2 = 0; c2 < 2; ++c2) {
            const int c = w + c2 * 4;
            areg[c2] = load16_sc(hb_cur + (size_t)(m0 + c * 8 + crow) * H_ + k0 + ckof);
        }
    };
    auto STORE_A = [&](int pb) {
        #pragma unroll
        for (int c2 = 0; c2 < 2; ++c2) {
            const int c = w + c2 * 4;
            *(bf16x8*)(Al0 + pb * 4096 + c * 512 + lane * 8) = areg[c2];
        }
    };
    auto STAGE_B = [&](int pb, int k0) {   // 3 lds-loads/wave (12 chunks)
        #pragma unroll
        for (int idx = w; idx < 12; idx += 4)
            stage16(rkt + (size_t)((idx >> 2) * H_ + i0 + (idx & 3) * 8 + crow) * H_ + k0 + ckof,
                    Bl0 + pb * 6144 + idx * 512, lane);
    };

    LOAD_A(0);
    STAGE_B(0, 0);
    wait_vm3();       // A (older) done; 3 B lds-loads still in flight
    STORE_A(0);
    __syncthreads();
    int buf = 0;
    for (int k0 = 0; k0 < H_; k0 += 64) {
        const bool more = (k0 + 64 < H_);
        if (more) { LOAD_A(k0 + 64); STAGE_B(buf ^ 1, k0 + 64); }
        #pragma unroll
        for (int kk = 0; kk < 2; ++kk) {
            const int ko = kk ? ko1 : ko0;
            bf16x8 af[2], bf[3];
            #pragma unroll
            for (int fm = 0; fm < 2; ++fm)
                af[fm] = *(const bf16x8*)(Al0 + buf * 4096 + (wr * 32 + fm * 16 + ln) * 64 + ko);
            #pragma unroll
            for (int g = 0; g < 3; ++g)
                bf[g] = *(const bf16x8*)(Bl0 + buf * 6144 + g * 2048 + ((w & 1) * 16 + ln) * 64 + ko);
            #pragma unroll
            for (int fm = 0; fm < 2; ++fm)
                #pragma unroll
                for (int g = 0; g < 3; ++g)
                    acc[fm][g] = __builtin_amdgcn_mfma_f32_16x16x32_bf16(
                        af[fm], bf[g], acc[fm][g], 0, 0, 0);
        }
        if (more) { wait_vm3(); STORE_A(buf ^ 1); }
        __syncthreads();
        buf ^= 1;
    }

    #pragma unroll
    for (int fm = 0; fm < 2; ++fm)
        #pragma unroll
        for (int r = 0; r < 4; ++r) {
            const int b = m0 + wr * 32 + fm * 16 + kg * 4 + r;
            const float hvv = hv[fm][r];
            float z  = sigmoidf_(xgz[fm][r] + acc[fm][0][r] + rbz);
            float rr = sigmoidf_(xgr[fm][r] + acc[fm][1][r] + rbr);
            float hh = tanhf(xgh[fm][r] + rr * (acc[fm][2][r] + rbh));
            float hn = (ids[fm][r] != 0) ? (z * hvv + (1.0f - z) * hh) : hvv;
            hv[fm][r] = hn;
            store_bf16_sc(hb_nxt + (size_t)b * H_ + i, hn);
        }
}

// ---------------------------------------------------------------------------
// Layer-2 phase body. State A-tiles reg-staged coherent; weights cached.
// lds: 28672 ushorts (56 KB).
// ---------------------------------------------------------------------------
__device__ __forceinline__ void l2_phase(
    ushort_t* lds,
    int m0, int i0, int i, int t,
    const int* __restrict__ tgt,
    const ushort_t* __restrict__ k2t, const ushort_t* __restrict__ rk2t,
    float bxz, float bxr, float bxh,
    float brz, float brr, float brh,
    const ushort_t* __restrict__ s1b,
    const ushort_t* __restrict__ a1, size_t a1s,
    __hip_bfloat16* __restrict__ hbo, size_t hos,
    float (&hv)[2][4])
{
    ushort_t* A0l = lds;            // 2 x 4096
    ushort_t* A1l = lds + 8192;     // 2 x 4096
    ushort_t* B0l = lds + 16384;    // 6144
    ushort_t* B1l = lds + 22528;    // 6144

    const int tid  = threadIdx.x;
    const int lane = tid & 63;
    const int w    = tid >> 6;
    const int ln   = lane & 15;
    const int kg   = lane >> 4;
    const int wr   = w >> 1;

    const int crow = lane >> 3;
    const int ckof = ((lane & 7) ^ crow) * 8;

    int ids[2][4];
    #pragma unroll
    for (int fm = 0; fm < 2; ++fm)
        #pragma unroll
        for (int r = 0; r < 4; ++r) {
            const int b = m0 + wr * 32 + fm * 16 + kg * 4 + r;
            ids[fm][r] = tgt[(size_t)b * T_ + t];
        }

    const int ko0 = (kg * 8) ^ ((ln & 7) * 8);
    const int ko1 = (32 + kg * 8) ^ ((ln & 7) * 8);

    bf16x8 areg[4];

    auto LOAD_A = [&](int k0) {     // 4 coherent loads/wave (16 chunks total)
        #pragma unroll
        for (int c2 = 0; c2 < 4; ++c2) {
            const int c = w + c2 * 4;
            const ushort_t* g = (c < 8)
                ? s1b + (size_t)(m0 + c * 8 + crow) * H_ + k0 + ckof
                : a1  + (size_t)(m0 + (c - 8) * 8 + crow) * a1s + k0 + ckof;
            areg[c2] = load16_sc(g);
        }
    };
    auto STORE_A = [&](int pb) {
        #pragma unroll
        for (int c2 = 0; c2 < 4; ++c2) {
            const int c = w + c2 * 4;
            ushort_t* l = (c < 8) ? A0l + pb * 4096 + c * 512
                                  : A1l + pb * 4096 + (c - 8) * 512;
            *(bf16x8*)(l + lane * 8) = areg[c2];
        }
    };
    auto STAGE_B = [&](int k0) {    // 6 lds-loads/wave (24 chunks total)
        #pragma unroll
        for (int c = w; c < 24; c += 4) {
            const ushort_t* g; ushort_t* l;
            if (c < 12) {
                g = k2t + (size_t)((c >> 2) * H_ + i0 + (c & 3) * 8 + crow) * H_ + k0 + ckof;
                l = B0l + c * 512;
            } else {
                const int idx = c - 12;
                g = rk2t + (size_t)((idx >> 2) * H_ + i0 + (idx & 3) * 8 + crow) * H_ + k0 + ckof;
                l = B1l + idx * 512;
            }
            stage16(g, l, lane);
        }
    };

    f32x4 acc0[2][3] = {};
    f32x4 acc1[2][3] = {};

    LOAD_A(0);
    STAGE_B(0);
    wait_vm6();       // A (older 4) done; 6 B lds-loads still in flight
    STORE_A(0);
    __syncthreads();
    int buf = 0;
    for (int k0 = 0; k0 < H_; k0 += 64) {
        const bool more = (k0 + 64 < H_);
        if (more) LOAD_A(k0 + 64);

        bf16x8 a0f[2][2], a1f[2][2], b0f[2][3], b1f[2][3];
        #pragma unroll
        for (int kk = 0; kk < 2; ++kk) {
            const int ko = kk ? ko1 : ko0;
            #pragma unroll
            for (int fm = 0; fm < 2; ++fm) {
                a0f[kk][fm] = *(const bf16x8*)(A0l + buf * 4096 + (wr * 32 + fm * 16 + ln) * 64 + ko);
                a1f[kk][fm] = *(const bf16x8*)(A1l + buf * 4096 + (wr * 32 + fm * 16 + ln) * 64 + ko);
            }
            #pragma unroll
            for (int g = 0; g < 3; ++g) {
                b0f[kk][g] = *(const bf16x8*)(B0l + g * 2048 + ((w & 1) * 16 + ln) * 64 + ko);
                b1f[kk][g] = *(const bf16x8*)(B1l + g * 2048 + ((w & 1) * 16 + ln) * 64 + ko);
            }
        }
        __builtin_amdgcn_sched_barrier(0);
        asm volatile("s_waitcnt lgkmcnt(0)" ::: "memory");
        __builtin_amdgcn_sched_barrier(0);
        __builtin_amdgcn_s_barrier();
        if (more) STAGE_B(k0 + 64);

        #pragma unroll
        for (int kk = 0; kk < 2; ++kk)
            #pragma unroll
            for (int fm = 0; fm < 2; ++fm)
                #pragma unroll
                for (int g = 0; g < 3; ++g) {
                    acc0[fm][g] = __builtin_amdgcn_mfma_f32_16x16x32_bf16(
                        a0f[kk][fm], b0f[kk][g], acc0[fm][g], 0, 0, 0);
                    acc1[fm][g] = __builtin_amdgcn_mfma_f32_16x16x32_bf16(
                        a1f[kk][fm], b1f[kk][g], acc1[fm][g], 0, 0, 0);
                }
        if (more) { wait_vm6(); STORE_A(buf ^ 1); }
        __syncthreads();
        buf ^= 1;
    }

    #pragma unroll
    for (int fm = 0; fm < 2; ++fm)
        #pragma unroll
        for (int r = 0; r < 4; ++r) {
            const int b = m0 + wr * 32 + fm * 16 + kg * 4 + r;
            const float hvv = hv[fm][r];
            float z  = sigmoidf_((acc0[fm][0][r] + bxz) + (acc1[fm][0][r] + brz));
            float rr = sigmoidf_((acc0[fm][1][r] + bxr) + (acc1[fm][1][r] + brr));
            float hh = tanhf((acc0[fm][2][r] + bxh) + rr * (acc1[fm][2][r] + brh));
            float hn = (ids[fm][r] != 0) ? (z * hvv + (1.0f - z) * hh) : hvv;
            hv[fm][r] = hn;
            store_bf16_sc(hbo + (size_t)b * hos + i, hn);
        }
}

// ---------------------------------------------------------------------------
// Standalone per-step wrappers (fallback path): global fp32 carry.
// ---------------------------------------------------------------------------
__global__ __launch_bounds__(256, 2) void l1_fused(
    const int* __restrict__ tgt, int t,
    const float* __restrict__ xe1, const ushort_t* __restrict__ rkt,
    const float* __restrict__ rb,
    const float* __restrict__ hf_cur, const ushort_t* __restrict__ hb_cur,
    float* __restrict__ hf_nxt, __hip_bfloat16* __restrict__ hb_nxt)
{
    __shared__ __attribute__((aligned(16))) ushort_t lds[20480];
    int m0, i0; tile_map(blockIdx.x, m0, i0);
    const int tid = threadIdx.x, lane = tid & 63, w = tid >> 6;
    const int ln = lane & 15, kg = lane >> 4, wr = w >> 1, wc = w & 1;
    const int i = i0 + wc * 16 + ln;

    float hv[2][4];
    #pragma unroll
    for (int fm = 0; fm < 2; ++fm)
        #pragma unroll
        for (int r = 0; r < 4; ++r)
            hv[fm][r] = hf_cur[(size_t)(m0 + wr * 32 + fm * 16 + kg * 4 + r) * H_ + i];

    l1_phase(lds, lds + 8192, m0, i0, i, t, tgt, xe1, rkt,
             rb[i], rb[H_ + i], rb[2 * H_ + i], hb_cur, hb_nxt, hv);

    #pragma unroll
    for (int fm = 0; fm < 2; ++fm)
        #pragma unroll
        for (int r = 0; r < 4; ++r)
            hf_nxt[(size_t)(m0 + wr * 32 + fm * 16 + kg * 4 + r) * H_ + i] = hv[fm][r];
}

__global__ __launch_bounds__(256, 2) void l2_fused(
    const int* __restrict__ tgt, int t,
    const ushort_t* __restrict__ k2t, const ushort_t* __restrict__ rk2t,
    const float* __restrict__ bx, const float* __restrict__ br,
    const ushort_t* __restrict__ s1b,
    const float* __restrict__ hf_cur,
    const ushort_t* __restrict__ hb_cur, size_t hbs,
    float* __restrict__ hf_nxt,
    __hip_bfloat16* __restrict__ hbo, size_t hos)
{
    __shared__ __attribute__((aligned(16))) ushort_t lds[28672];
    int m0, i0; tile_map(blockIdx.x, m0, i0);
    const int tid = threadIdx.x, lane = tid & 63, w = tid >> 6;
    const int ln = lane & 15, kg = lane >> 4, wr = w >> 1, wc = w & 1;
    const int i = i0 + wc * 16 + ln;

    float hv[2][4];
    #pragma unroll
    for (int fm = 0; fm < 2; ++fm)
        #pragma unroll
        for (int r = 0; r < 4; ++r)
            hv[fm][r] = hf_cur[(size_t)(m0 + wr * 32 + fm * 16 + kg * 4 + r) * H_ + i];

    l2_phase(lds, m0, i0, i, t, tgt, k2t, rk2t,
             bx[i], bx[H_ + i], bx[2 * H_ + i],
             br[i], br[H_ + i], br[2 * H_ + i],
             s1b, hb_cur, hbs, hbo, hos, hv);

    #pragma unroll
    for (int fm = 0; fm < 2; ++fm)
        #pragma unroll
        for (int r = 0; r < 4; ++r)
            hf_nxt[(size_t)(m0 + wr * 32 + fm * 16 + kg * 4 + r) * H_ + i] = hv[fm][r];
}

// ---------------------------------------------------------------------------
// Grid barrier: NO fences (L2 stays warm). Cross-block data is exchanged
// exclusively through sc0/sc1 (coherence-point) loads/stores, which are
// drained by the explicit vmcnt(0) before arrival.
// ---------------------------------------------------------------------------
__device__ __forceinline__ void grid_barrier(unsigned* bar, unsigned phase)
{
    asm volatile("s_waitcnt vmcnt(0)" ::: "memory");  // drain asm sc-stores
    __syncthreads();
    if (threadIdx.x == 0) {
        const unsigned arrived =
            __hip_atomic_fetch_add(&bar[0], 1u, __ATOMIC_RELAXED, __HIP_MEMORY_SCOPE_AGENT) + 1u;
        if (arrived == (unsigned)NBLK_ * (phase + 1u)) {
            __hip_atomic_store(&bar[1], phase + 1u, __ATOMIC_RELAXED, __HIP_MEMORY_SCOPE_AGENT);
        } else {
            while (__hip_atomic_load(&bar[1], __ATOMIC_RELAXED, __HIP_MEMORY_SCOPE_AGENT) < phase + 1u)
                __builtin_amdgcn_s_sleep(4);
        }
    }
    __syncthreads();
}

// ---------------------------------------------------------------------------
// Persistent recurrence: separate l1/l2 phases, 2 fence-free barriers/step,
// register fp32 carry, i0-pinned tiles (weights L2-resident all 48 steps).
// ---------------------------------------------------------------------------
__global__ __launch_bounds__(256, 2) void recurrence_all(
    const int* __restrict__ tgt, const float* __restrict__ xe1,
    const ushort_t* __restrict__ rk1t, const float* __restrict__ rb1,
    const ushort_t* __restrict__ k2t, const ushort_t* __restrict__ rk2t,
    const float* __restrict__ bx, const float* __restrict__ br,
    const float* __restrict__ h1f0, __hip_bfloat16* __restrict__ h1b,
    const float* __restrict__ h2f0, const __hip_bfloat16* __restrict__ h2b0,
    __hip_bfloat16* __restrict__ seq2b, unsigned* __restrict__ bar)
{
    __shared__ __attribute__((aligned(16))) ushort_t lds[28672];  // 56 KB
    int m0, i0; tile_map(blockIdx.x, m0, i0);
    const int tid = threadIdx.x, lane = tid & 63, w = tid >> 6;
    const int ln = lane & 15, kg = lane >> 4, wr = w >> 1, wc = w & 1;
    const int i = i0 + wc * 16 + ln;

    const float rbz = rb1[i], rbr = rb1[H_ + i], rbh = rb1[2 * H_ + i];
    const float bxz = bx[i],  bxr = bx[H_ + i],  bxh = bx[2 * H_ + i];
    const float brz = br[i],  brr = br[H_ + i],  brh = br[2 * H_ + i];

    float hv1[2][4], hv2[2][4];
    #pragma unroll
    for (int fm = 0; fm < 2; ++fm)
        #pragma unroll
        for (int r = 0; r < 4; ++r) {
            const size_t b = (size_t)(m0 + wr * 32 + fm * 16 + kg * 4 + r) * H_ + i;
            hv1[fm][r] = h1f0[b];
            hv2[fm][r] = h2f0[b];
        }

    unsigned ph = 0;

    #pragma unroll 1
    for (int t = 0; t < T_; ++t) {
        const int cur = t & 1, nxt = cur ^ 1;

        l1_phase(lds, lds + 8192, m0, i0, i, t, tgt, xe1, rk1t,
                 rbz, rbr, rbh,
                 (const ushort_t*)(h1b + (size_t)cur * BH_),
                 h1b + (size_t)nxt * BH_, hv1);
        grid_barrier(bar, ph); ++ph;

        const ushort_t* a1 = (t == 0)
            ? (const ushort_t*)h2b0
            : (const ushort_t*)(seq2b + (size_t)(t - 1) * H_);
        const size_t a1s = (t == 0) ? (size_t)H_ : (size_t)T_ * H_;

        l2_phase(lds, m0, i0, i, t, tgt, k2t, rk2t,
                 bxz, bxr, bxh, brz, brr, brh,
                 (const ushort_t*)(h1b + (size_t)nxt * BH_),
                 a1, a1s,
                 seq2b + (size_t)t * H_, (size_t)T_ * H_, hv2);
        if (t + 1 < T_) { grid_barrier(bar, ph); ++ph; }
    }
}

// ---------------------------------------------------------------------------
// Softmax helpers + per-step fallback kernel (small-workspace path)
// ---------------------------------------------------------------------------
__device__ __forceinline__ void softmax_write4(
    float ax, float ay, float az, float aw, float* __restrict__ outp, int cg)
{
    float m = fmaxf(fmaxf(ax, ay), fmaxf(az, aw));
    #pragma unroll
    for (int d = 16; d >= 1; d >>= 1) m = fmaxf(m, __shfl_xor(m, d));
    float ex = __expf(ax - m), ey = __expf(ay - m),
          ez = __expf(az - m), ew = __expf(aw - m);
    float s = ex + ey + ez + ew;
    #pragma unroll
    for (int d = 16; d >= 1; d >>= 1) s += __shfl_xor(s, d);
    float inv = 1.0f / s;
    float4 o; o.x = ex * inv; o.y = ey * inv; o.z = ez * inv; o.w = ew * inv;
    *(float4*)(outp + cg * 4) = o;
}

__global__ __launch_bounds__(256) void out_softmax(
    const float* __restrict__ h2, const float* __restrict__ Wv,
    const float* __restrict__ bv, float* __restrict__ out, int t)
{
    const int tid = threadIdx.x;
    const int cg = tid & 31;
    const int rg = tid >> 5;
    const int row0 = blockIdx.x * 16;

    __shared__ float hs[16][512];
    for (int idx = tid; idx < 16 * 512; idx += 256)
        hs[idx >> 9][idx & 511] = h2[(size_t)(row0 + (idx >> 9)) * 512 + (idx & 511)];
    __syncthreads();

    const int r0 = rg * 2;
    const float4 bvv = *(const float4*)(bv + cg * 4);
    float a0x = bvv.x, a0y = bvv.y, a0z = bvv.z, a0w = bvv.w;
    float a1x = bvv.x, a1y = bvv.y, a1z = bvv.z, a1w = bvv.w;

    #pragma unroll 4
    for (int k = 0; k < 512; ++k) {
        float4 wv = *(const float4*)(Wv + (size_t)k * V_ + cg * 4);
        float h0 = hs[r0][k], h1 = hs[r0 + 1][k];
        a0x += h0 * wv.x; a0y += h0 * wv.y; a0z += h0 * wv.z; a0w += h0 * wv.w;
        a1x += h1 * wv.x; a1y += h1 * wv.y; a1z += h1 * wv.z; a1w += h1 * wv.w;
    }

    softmax_write4(a0x, a0y, a0z, a0w, out + ((size_t)(row0 + r0) * T_ + t) * V_, cg);
    softmax_write4(a1x, a1y, a1z, a1w, out + ((size_t)(row0 + r0 + 1) * T_ + t) * V_, cg);
}

// ---------------------------------------------------------------------------
// Batched MFMA vocab projection + softmax (off critical path).
// ---------------------------------------------------------------------------
__global__ __launch_bounds__(256) void proj_mfma(
    const ushort_t* __restrict__ s2, const ushort_t* __restrict__ wvt,
    const float* __restrict__ bv, float* __restrict__ out)
{
    const int lane = threadIdx.x & 63;
    const int w    = threadIdx.x >> 6;
    const int ln   = lane & 15;
    const int kg   = lane >> 4;
    const size_t row0 = (size_t)blockIdx.x * 128 + (size_t)w * 32;

    float bvl[8];
    #pragma unroll
    for (int nf = 0; nf < 8; ++nf) bvl[nf] = bv[nf * 16 + ln];

    f32x4 acc[2][8] = {};
    #pragma unroll 2
    for (int k0 = 0; k0 < H_; k0 += 32) {
        bf16x8 af[2], bf[8];
        #pragma unroll
        for (int mf = 0; mf < 2; ++mf)
            af[mf] = *(const bf16x8*)(s2 + (row0 + mf * 16 + ln) * H_ + k0 + kg * 8);
        #pragma unroll
        for (int nf = 0; nf < 8; ++nf)
            bf[nf] = *(const bf16x8*)(wvt + (size_t)(nf * 16 + ln) * H_ + k0 + kg * 8);
        #pragma unroll
        for (int mf = 0; mf < 2; ++mf)
            #pragma unroll
            for (int nf = 0; nf < 8; ++nf)
                acc[mf][nf] = __builtin_amdgcn_mfma_f32_16x16x32_bf16(
                    af[mf], bf[nf], acc[mf][nf], 0, 0, 0);
    }

    #pragma unroll
    for (int mf = 0; mf < 2; ++mf)
        #pragma unroll
        for (int q = 0; q < 4; ++q) {
            float v[8];
            float m = -1e30f;
            #pragma unroll
            for (int nf = 0; nf < 8; ++nf) { v[nf] = acc[mf][nf][q] + bvl[nf]; m = fmaxf(m, v[nf]); }
            #pragma unroll
            for (int d = 1; d <= 8; d <<= 1) m = fmaxf(m, __shfl_xor(m, d));
            float s = 0.f;
            #pragma unroll
            for (int nf = 0; nf < 8; ++nf) { v[nf] = __expf(v[nf] - m); s += v[nf]; }
            #pragma unroll
            for (int d = 1; d <= 8; d <<= 1) s += __shfl_xor(s, d);
            const float inv = 1.0f / s;
            float* op = out + (row0 + mf * 16 + kg * 4 + q) * V_;
            #pragma unroll
            for (int nf = 0; nf < 8; ++nf) op[nf * 16 + ln] = v[nf] * inv;
        }
}

// ---------------------------------------------------------------------------
// Launch
// ---------------------------------------------------------------------------
extern "C" void kernel_launch(void* const* d_in, const int* in_sizes, int n_in,
                              void* d_out, int out_size, void* d_ws, size_t ws_size,
                              hipStream_t stream)
{
    const int*   tgt  = (const int*)  d_in[0];
    const float* enc  = (const float*)d_in[1];
    const float* Wi1  = (const float*)d_in[2];
    const float* Wi2  = (const float*)d_in[3];
    const float* emb  = (const float*)d_in[4];
    const float* k1   = (const float*)d_in[5];
    const float* rk1  = (const float*)d_in[6];
    const float* b1   = (const float*)d_in[7];
    const float* k2   = (const float*)d_in[8];
    const float* rk2  = (const float*)d_in[9];
    const float* b2   = (const float*)d_in[10];
    const float* Wv   = (const float*)d_in[11];
    const float* bv   = (const float*)d_in[12];
    float* out = (float*)d_out;

    // workspace layout
    float* ws  = (float*)d_ws;
    float* xe1 = ws;                                   // [V,3H] f32
    float* h1f = xe1 + (size_t)V_ * H3_;               // [2][B*H] f32
    float* h2f = h1f + (size_t)2 * BH_;                // [2][B*H] f32
    __hip_bfloat16* h1b = (__hip_bfloat16*)(h2f + (size_t)2 * BH_);  // [2][B*H]
    __hip_bfloat16* h2b = h1b + (size_t)2 * BH_;       // [2][B*H]
    __hip_bfloat16* rk1t = h2b + (size_t)2 * BH_;      // [3H,H]
    __hip_bfloat16* k2t  = rk1t + (size_t)H3_ * H_;
    __hip_bfloat16* rk2t = k2t  + (size_t)H3_ * H_;
    __hip_bfloat16* wvt  = rk2t + (size_t)H3_ * H_;    // [V,H]
    __hip_bfloat16* ehi  = wvt + (size_t)V_ * H_;      // [B,ENC]
    __hip_bfloat16* elo  = ehi + (size_t)B_ * ENC_;
    __hip_bfloat16* w1hi = elo + (size_t)B_ * ENC_;    // [H,ENC] x4
    __hip_bfloat16* w1lo = w1hi + (size_t)H_ * ENC_;
    __hip_bfloat16* w2hi = w1lo + (size_t)H_ * ENC_;
    __hip_bfloat16* w2lo = w2hi + (size_t)H_ * ENC_;
    __hip_bfloat16* seq2b = w2lo + (size_t)H_ * ENC_;  // [B,T,H] bf16
    unsigned* bar = (unsigned*)(seq2b + (size_t)B_ * T_ * H_);  // 64 B

    const size_t need = (size_t)((char*)bar + 64 - (char*)d_ws);
    const bool batched = ws_size >= need;

    static int persist_state = -1;
    if (persist_state < 0) {
        int nb = 0;
        hipError_t e1 = hipOccupancyMaxActiveBlocksPerMultiprocessor(&nb, recurrence_all, 256, 0);
        hipDeviceProp_t prop;
        hipError_t e2 = hipGetDeviceProperties(&prop, 0);
        persist_state = (e1 == hipSuccess && e2 == hipSuccess &&
                         (long)nb * prop.multiProcessorCount >= NBLK_) ? 1 : 0;
    }
    const bool persist = batched && persist_state == 1;

    dim3 blk(256);

    // one-time: weight transposes to bf16
    transpose_to_bf16<<<dim3(H3_ / 32, H_ / 32), blk, 0, stream>>>(rk1, rk1t, H_, H3_);
    transpose_to_bf16<<<dim3(H3_ / 32, H_ / 32), blk, 0, stream>>>(k2,  k2t,  H_, H3_);
    transpose_to_bf16<<<dim3(H3_ / 32, H_ / 32), blk, 0, stream>>>(rk2, rk2t, H_, H3_);
    if (batched)
        transpose_to_bf16<<<dim3(V_ / 32, H_ / 32), blk, 0, stream>>>(Wv, wvt, H_, V_);

    // split-bf16 operands for the exact MFMA h0-init
    split_cast<<<dim3((B_ * ENC_) / 1024), blk, 0, stream>>>(enc, ehi, elo, B_ * ENC_);
    transpose_split<<<dim3(H_ / 32, ENC_ / 32), blk, 0, stream>>>(Wi1, w1hi, w1lo, ENC_, H_);
    transpose_split<<<dim3(H_ / 32, ENC_ / 32), blk, 0, stream>>>(Wi2, w2hi, w2lo, ENC_, H_);

    // xe1 = embed_table @ k1 + b1[0]  (fp32, exact)
    gemm_f32<<<dim3(H3_ / BN, V_ / BM), blk, 0, stream>>>(emb, k1, b1, xe1, V_, H3_, E_);

    // h0-init
    init_mfma<<<dim3(H_ / 32, B_ / 64, 2), blk, 0, stream>>>(
        (const ushort_t*)ehi, (const ushort_t*)elo,
        (const ushort_t*)w1hi, (const ushort_t*)w1lo,
        (const ushort_t*)w2hi, (const ushort_t*)w2lo,
        h1f, h1b, h2f, h2b);

    if (persist) {
        hipMemsetAsync(bar, 0, 64, stream);
        recurrence_all<<<dim3(NBLK_), blk, 0, stream>>>(
            tgt, xe1, (const ushort_t*)rk1t, b1 + H3_,
            (const ushort_t*)k2t, (const ushort_t*)rk2t, b2, b2 + H3_,
            h1f, h1b, h2f, h2b, seq2b, bar);
        proj_mfma<<<dim3((B_ * T_) / 128), blk, 0, stream>>>(
            (const ushort_t*)seq2b, (const ushort_t*)wvt, bv, out);
        return;
    }

    // fallback: per-step launches
    const dim3 fgrid(NBLK_);
    for (int t = 0; t < T_; ++t) {
        const int cur = t & 1, nxt = cur ^ 1;
        float* h1f_c = h1f + (size_t)cur * BH_;
        float* h1f_n = h1f + (size_t)nxt * BH_;
        float* h2f_c = h2f + (size_t)cur * BH_;
        float* h2f_n = h2f + (size_t)nxt * BH_;
        __hip_bfloat16* h1b_c = h1b + (size_t)cur * BH_;
        __hip_bfloat16* h1b_n = h1b + (size_t)nxt * BH_;

        l1_fused<<<fgrid, blk, 0, stream>>>(
            tgt, t, xe1, (const ushort_t*)rk1t, b1 + H3_,
            h1f_c, (const ushort_t*)h1b_c, h1f_n, h1b_n);

        const ushort_t* hb_c; size_t hbs;
        __hip_bfloat16* hbo; size_t hos;
        if (batched) {
            hb_c = (t == 0) ? (const ushort_t*)h2b
                            : (const ushort_t*)(seq2b + (size_t)(t - 1) * H_);
            hbs  = (t == 0) ? (size_t)H_ : (size_t)T_ * H_;
            hbo  = seq2b + (size_t)t * H_;
            hos  = (size_t)T_ * H_;
        } else {
            hb_c = (const ushort_t*)(h2b + (size_t)cur * BH_); hbs = H_;
            hbo  = h2b + (size_t)nxt * BH_;                    hos = H_;
        }

        l2_fused<<<fgrid, blk, 0, stream>>>(
            tgt, t, (const ushort_t*)k2t, (const ushort_t*)rk2t, b2, b2 + H3_,
            (const ushort_t*)h1b_n, h2f_c, hb_c, hbs, h2f_n, hbo, hos);

        if (!batched)
            out_softmax<<<dim3(B_ / 16), blk, 0, stream>>>(h2f_n, Wv, bv, out, t);
    }

    if (batched)
        proj_mfma<<<dim3((B_ * T_) / 128), blk, 0, stream>>>(
            (const ushort_t*)seq2b, (const ushort_t*)wvt, bv, out);
}